// Round 6
// baseline (155.897 us; speedup 1.0000x reference)
//
#include <hip/hip_runtime.h>

#define BB 8
#define CC 128
#define HH 96
#define WW 96
#define LL 9216
#define EPSF 1e-5f

typedef __attribute__((ext_vector_type(8))) short short8;
typedef __attribute__((ext_vector_type(4))) float f32x4;
typedef __attribute__((ext_vector_type(4))) unsigned int uint32x4;
typedef unsigned short ushort_t;
typedef unsigned int uint32;

__device__ __forceinline__ float silu_f(float x){ return x / (1.0f + __expf(-x)); }
__device__ __forceinline__ ushort_t f2bf(float f){
    uint32 u = __float_as_uint(f);
    u += 0x7FFFu + ((u >> 16) & 1u);          // RNE
    return (ushort_t)(u >> 16);
}
__device__ __forceinline__ float bf2f(ushort_t h){ return __uint_as_float(((uint32)h) << 16); }
__device__ __forceinline__ uint32 pack2(float a, float b){
    return (uint32)f2bf(a) | ((uint32)f2bf(b) << 16);
}

// ---------------------------------------------------------------------------
// Convert W_in/W_out fp32 -> bf16; also emit dwT[j][c] = dw_w[c][j] (fp32).
// grid 128 x 256.
// ---------------------------------------------------------------------------
__global__ void k_prep(const float* __restrict__ Win, const float* __restrict__ Wout,
                       const float* __restrict__ dw_w,
                       ushort_t* __restrict__ WinB, ushort_t* __restrict__ WoutB,
                       float* __restrict__ dwT){
    int i = blockIdx.x * 256 + threadIdx.x;
    if (i < 256 * 128) WinB[i] = f2bf(Win[i]);
    if (i < 128 * 128) WoutB[i] = f2bf(Wout[i]);
    if (i < 7 * 128){
        int j = i >> 7, c = i & 127;
        dwT[i] = dw_w[c * 7 + j];
    }
}

// ---------------------------------------------------------------------------
// GEMM A (fused transpose): reads x (B,128,L) fp32 directly.
// Stage fp32 tile -> pack bf16 token-major into swizzled LDS -> MFMA ->
// U = silu(uv[0:128]), V = uv[128:256], token-major bf16 (B,L,128).
// grid(144,B) x 256.
// ---------------------------------------------------------------------------
__global__ __launch_bounds__(256) void k_gemmA(const float* __restrict__ x,
        const ushort_t* __restrict__ WinB, const float* __restrict__ b_in,
        ushort_t* __restrict__ U, ushort_t* __restrict__ V){
    __shared__ __align__(16) char unia[36864];          // xt fp32 | eb (union)
    float (*xt)[65] = (float(*)[65])unia;               // [128][65]
    ushort_t (*eb)[64][72] = (ushort_t(*)[64][72])unia; // [4][64][72]
    __shared__ __align__(16) ushort_t xtile[64 * 128];  // swizzled token-major

    const int b = blockIdx.y, l0 = blockIdx.x * 64, tid = threadIdx.x;
    const int wv = tid >> 6, lane = tid & 63;
    const int lo = lane & 15, hi = lane >> 4;
    const int o0 = wv * 64;

    #pragma unroll
    for (int k = 0; k < 32; ++k){
        int c = (tid >> 6) + k * 4;
        xt[c][lane] = x[((size_t)(b * 128 + c)) * LL + l0 + lane];
    }
    __syncthreads();
    #pragma unroll
    for (int p = 0; p < 16; ++p){
        int l = (tid >> 6) + p * 4;
        uint32 v = pack2(xt[2 * lane][l], xt[2 * lane + 1][l]);
        *(uint32*)((char*)xtile + l * 256 + ((lane * 4) ^ ((l & 7) << 4))) = v;
    }
    __syncthreads();

    const f32x4 zero = {0.f, 0.f, 0.f, 0.f};
    f32x4 acc[4][4];
    #pragma unroll
    for (int om = 0; om < 4; ++om)
        #pragma unroll
        for (int lf = 0; lf < 4; ++lf) acc[om][lf] = zero;

    #pragma unroll
    for (int ks = 0; ks < 4; ++ks){
        short8 af[4], bfr[4];
        #pragma unroll
        for (int om = 0; om < 4; ++om)
            af[om] = *(const short8*)(WinB + (size_t)(o0 + om * 16 + lo) * 128 + ks * 32 + hi * 8);
        #pragma unroll
        for (int lf = 0; lf < 4; ++lf){
            int tok = lf * 16 + lo;
            bfr[lf] = *(const short8*)((char*)xtile + tok * 256 +
                        ((ks * 64 + hi * 16) ^ ((tok & 7) << 4)));
        }
        #pragma unroll
        for (int om = 0; om < 4; ++om)
            #pragma unroll
            for (int lf = 0; lf < 4; ++lf)
                acc[om][lf] = __builtin_amdgcn_mfma_f32_16x16x32_bf16(af[om], bfr[lf], acc[om][lf], 0, 0, 0);
    }

    const bool isU = (wv < 2);
    #pragma unroll
    for (int om = 0; om < 4; ++om){
        int ob = o0 + om * 16 + hi * 4;
        f32x4 bia = *(const f32x4*)(b_in + ob);
        #pragma unroll
        for (int lf = 0; lf < 4; ++lf){
            f32x4 v = acc[om][lf];
            float v0 = v[0] + bia[0], v1 = v[1] + bia[1];
            float v2 = v[2] + bia[2], v3 = v[3] + bia[3];
            if (isU){ v0 = silu_f(v0); v1 = silu_f(v1); v2 = silu_f(v2); v3 = silu_f(v3); }
            int ll = lf * 16 + lo;
            uint32* row = (uint32*)(&eb[wv][ll][0]);
            row[om * 8 + hi * 2    ] = pack2(v0, v1);
            row[om * 8 + hi * 2 + 1] = pack2(v2, v3);
        }
    }
    __syncthreads();

    uint32* Ub = (uint32*)(U + (size_t)b * LL * 128);
    uint32* Vb = (uint32*)(V + (size_t)b * LL * 128);
    const int wsrc = lane >> 5, jcol = lane & 31;
    #pragma unroll
    for (int p = 0; p < 16; ++p){
        int l = (tid >> 6) + p * 4;
        uint32 vu = ((uint32*)&eb[0 + wsrc][l][0])[jcol];
        uint32 vv = ((uint32*)&eb[2 + wsrc][l][0])[jcol];
        Ub[(size_t)(l0 + l) * 64 + lane] = vu;
        Vb[(size_t)(l0 + l) * 64 + lane] = vv;
    }
}

// ---------------------------------------------------------------------------
// Fused mixer + output GEMM, lane = (channel-slice, token).
// block 256 = 4 waves, 16 tokens. Within a wave: tl=lane&3 (token),
// cs=lane>>2 (16 slices x 8ch = 128 ch). Tap loads: 16B/lane covering
// 4 token-rows x 256B -> fully coalesced. LN channel-reduction: 4x shfl_xor
// (lane bits 2..5) -> no barriers, no LDS. Single barrier before the fused
// 16-token out-GEMM (ytile 4KB swizzled LDS), direct global stores.
// grid(576, B) x 256.
// ---------------------------------------------------------------------------
__global__ __launch_bounds__(256, 4) void k_mixout(const ushort_t* __restrict__ U,
        const ushort_t* __restrict__ V, const float* __restrict__ dwT,
        const float* __restrict__ dw_b, const float* __restrict__ gamma,
        const float* __restrict__ beta, const ushort_t* __restrict__ WoutB,
        const float* __restrict__ b_out, float* __restrict__ out){
    __shared__ __align__(16) ushort_t ytile[16 * 128];
    const int b   = blockIdx.y;
    const int m0  = blockIdx.x * 16;
    const int tid = threadIdx.x;
    const int lane = tid & 63;
    const int wv  = tid >> 6;
    const int tl  = lane & 3;
    const int cs  = lane >> 2;       // 0..15
    const int c0  = cs * 8;
    const int tk  = wv * 4 + tl;     // token in tile
    const int m   = m0 + tk;
    const int h_l = m / WW, w_l = m - h_l * WW;

    const size_t base = (size_t)b * LL * 128;
    const ushort_t* Vb = V + base;

    // per-lane conv weights (8 ch x 7 taps) from transposed table
    float cw[7][8];
    #pragma unroll
    for (int j = 0; j < 7; ++j){
        f32x4 wa = *(const f32x4*)(dwT + j * 128 + c0);
        f32x4 wb = *(const f32x4*)(dwT + j * 128 + c0 + 4);
        cw[j][0] = wa[0]; cw[j][1] = wa[1]; cw[j][2] = wa[2]; cw[j][3] = wa[3];
        cw[j][4] = wb[0]; cw[j][5] = wb[1]; cw[j][6] = wb[2]; cw[j][7] = wb[3];
    }

    float uf[8];
    {
        short8 u8 = *(const short8*)(U + base + (size_t)m * 128 + c0);
        #pragma unroll
        for (int i = 0; i < 8; ++i) uf[i] = bf2f((ushort_t)u8[i]);
    }

    float ysr[8];
    #pragma unroll
    for (int i = 0; i < 8; ++i) ysr[i] = 0.f;

    auto do_pair = [&](const int* off){
        float ca[8], cb[8];
        {
            f32x4 ba = *(const f32x4*)(dw_b + c0);
            f32x4 bb = *(const f32x4*)(dw_b + c0 + 4);
            ca[0]=cb[0]=ba[0]; ca[1]=cb[1]=ba[1]; ca[2]=cb[2]=ba[2]; ca[3]=cb[3]=ba[3];
            ca[4]=cb[4]=bb[0]; ca[5]=cb[5]=bb[1]; ca[6]=cb[6]=bb[2]; ca[7]=cb[7]=bb[3];
        }
        #pragma unroll
        for (int j = 0; j < 7; ++j){
            short8 t = {0,0,0,0,0,0,0,0};
            if (off[j] >= 0) t = *(const short8*)(Vb + (size_t)off[j] * 128 + c0);
            #pragma unroll
            for (int i = 0; i < 8; ++i){
                float tv = bf2f((ushort_t)t[i]);
                ca[i] = fmaf(cw[j][i],     tv, ca[i]);   // forward kernel
                cb[i] = fmaf(cw[6 - j][i], tv, cb[i]);   // flipped (reversed dir)
            }
        }
        float ya[8], yb[8];
        float sa = 0.f, qa = 0.f, sb = 0.f, qb = 0.f;
        #pragma unroll
        for (int i = 0; i < 8; ++i){
            float va = uf[i] * silu_f(ca[i]);
            float vb = uf[i] * silu_f(cb[i]);
            ya[i] = va; yb[i] = vb;
            sa += va; qa += va * va; sb += vb; qb += vb * vb;
        }
        // reduce across the 16 channel-slices (lane bits 2..5)
        #pragma unroll
        for (int msk = 4; msk <= 32; msk <<= 1){
            sa += __shfl_xor(sa, msk);
            qa += __shfl_xor(qa, msk);
            sb += __shfl_xor(sb, msk);
            qb += __shfl_xor(qb, msk);
        }
        const float inv = 1.f / 128.f;
        float mua = sa * inv, vara = qa * inv - mua * mua;
        float mub = sb * inv, varb = qb * inv - mub * mub;
        float ra = rsqrtf(vara + EPSF), rb = rsqrtf(varb + EPSF);
        #pragma unroll
        for (int i = 0; i < 8; ++i)
            ysr[i] += (ya[i] - mua) * ra + (yb[i] - mub) * rb;
    };

    // pair 1: lr + rl (flat row-major taps)
    {
        int offH[7];
        #pragma unroll
        for (int j = 0; j < 7; ++j){
            int g = m + j - 3;
            offH[j] = (g >= 0 && g < LL) ? g : -1;
        }
        do_pair(offH);
    }
    // pair 2: tb + bt (col-major taps; closed form with column-wrap fixup)
    {
        int offV[7];
        #pragma unroll
        for (int j = 0; j < 7; ++j){
            int d  = j - 3;
            int hd = h_l + d;
            int q  = w_l * HH + hd;                 // col-major flat pos
            int t2 = m + WW * d + (hd < 0 ? (LL - 1) : (hd >= HH ? -(LL - 1) : 0));
            offV[j] = (q >= 0 && q < LL) ? t2 : -1;
        }
        do_pair(offV);
    }

    // sum_dirs LN = gamma*ysr + 4*beta; *0.25 -> bf16 -> swizzled ytile row
    {
        f32x4 g0 = *(const f32x4*)(gamma + c0);
        f32x4 g1 = *(const f32x4*)(gamma + c0 + 4);
        f32x4 e0 = *(const f32x4*)(beta + c0);
        f32x4 e1 = *(const f32x4*)(beta + c0 + 4);
        float gg[8] = {g0[0],g0[1],g0[2],g0[3],g1[0],g1[1],g1[2],g1[3]};
        float ee[8] = {e0[0],e0[1],e0[2],e0[3],e1[0],e1[1],e1[2],e1[3]};
        uint32 pk[4];
        #pragma unroll
        for (int p = 0; p < 4; ++p)
            pk[p] = pack2(0.25f * gg[2*p] * ysr[2*p] + ee[2*p],
                          0.25f * gg[2*p+1] * ysr[2*p+1] + ee[2*p+1]);
        uint32x4 s0 = {pk[0], pk[1], pk[2], pk[3]};
        *(uint32x4*)((char*)ytile + tk * 256 + ((cs * 16) ^ ((tk & 7) << 4))) = s0;
    }
    __syncthreads();

    // ---- fused out-GEMM: 128 o x 16 tok; wave wv owns o in [32wv, 32wv+32)
    const int lo = lane & 15, hi = lane >> 4;
    const f32x4 zero = {0.f, 0.f, 0.f, 0.f};
    f32x4 acc[2] = {zero, zero};
    #pragma unroll
    for (int ks = 0; ks < 4; ++ks){
        short8 bfr = *(const short8*)((char*)ytile + lo * 256 +
                        ((ks * 64 + hi * 16) ^ ((lo & 7) << 4)));
        #pragma unroll
        for (int om = 0; om < 2; ++om){
            short8 af = *(const short8*)(WoutB + (size_t)(wv * 32 + om * 16 + lo) * 128 + ks * 32 + hi * 8);
            acc[om] = __builtin_amdgcn_mfma_f32_16x16x32_bf16(af, bfr, acc[om], 0, 0, 0);
        }
    }
    #pragma unroll
    for (int om = 0; om < 2; ++om){
        int ob = wv * 32 + om * 16 + hi * 4;
        f32x4 bia = *(const f32x4*)(b_out + ob);
        #pragma unroll
        for (int r = 0; r < 4; ++r)
            out[((size_t)(b * 128 + ob + r)) * LL + m0 + lo] = acc[om][r] + bia[r];
    }
}

// ---------------------------------------------------------------------------
extern "C" void kernel_launch(void* const* d_in, const int* in_sizes, int n_in,
                              void* d_out, int out_size, void* d_ws, size_t ws_size,
                              hipStream_t stream) {
    const float* x     = (const float*)d_in[0];
    const float* W_in  = (const float*)d_in[1];
    const float* b_in  = (const float*)d_in[2];
    const float* dw_w  = (const float*)d_in[3];
    const float* dw_b  = (const float*)d_in[4];
    const float* gamma = (const float*)d_in[5];
    const float* beta  = (const float*)d_in[6];
    const float* W_out = (const float*)d_in[7];
    const float* b_out = (const float*)d_in[8];
    float* out = (float*)d_out;

    const size_t NTOK = (size_t)BB * LL;          // 73728
    ushort_t* U     = (ushort_t*)d_ws;            // (B,L,128) bf16
    ushort_t* V     = U + NTOK * 128;             // (B,L,128) bf16
    ushort_t* WinB  = V + NTOK * 128;             // 256x128 bf16
    ushort_t* WoutB = WinB + 256 * 128;           // 128x128 bf16
    float*    dwT   = (float*)(WoutB + 128 * 128);// [7][128] fp32 transposed

    k_prep<<<128, 256, 0, stream>>>(W_in, W_out, dw_w, WinB, WoutB, dwT);

    dim3 gA(LL / 64, BB);
    k_gemmA<<<gA, 256, 0, stream>>>(x, WinB, b_in, U, V);

    dim3 gM(LL / 16, BB);
    k_mixout<<<gM, 256, 0, stream>>>(U, V, dwT, dw_b, gamma, beta,
                                     WoutB, b_out, out);
}

// Round 7
// 134.860 us; speedup vs baseline: 1.1560x; 1.1560x over previous
//
#include <hip/hip_runtime.h>

#define BB 8
#define HH 96
#define WW 96
#define LL 9216
#define EPSF 1e-5f

typedef __attribute__((ext_vector_type(8))) short short8;
typedef __attribute__((ext_vector_type(4))) float f32x4;
typedef __attribute__((ext_vector_type(4))) unsigned int uint32x4;
typedef unsigned short ushort_t;
typedef unsigned int uint32;

__device__ __forceinline__ float silu_f(float x){ return x / (1.0f + __expf(-x)); }
__device__ __forceinline__ ushort_t f2bf(float f){
    uint32 u = __float_as_uint(f);
    u += 0x7FFFu + ((u >> 16) & 1u);          // RNE
    return (ushort_t)(u >> 16);
}
__device__ __forceinline__ float bf2f(short h){
    return __uint_as_float(((uint32)(ushort_t)h) << 16);
}
__device__ __forceinline__ uint32 pack2(float a, float b){
    return (uint32)f2bf(a) | ((uint32)f2bf(b) << 16);
}

// ---------------------------------------------------------------------------
// k_prep: W_in/W_out fp32 -> bf16 in MFMA A-fragment order
//   W2[((of*4+ks)*64 + lane)*8 + e] = W[of*16 + (lane&15)][ks*32 + (lane>>4)*8 + e]
// plus dwT[j][c] = dw_w[c][j] fp32.  grid 128 x 256.
// ---------------------------------------------------------------------------
__global__ __launch_bounds__(256) void k_prep(const float* __restrict__ Win,
        const float* __restrict__ Wout, const float* __restrict__ dw_w,
        ushort_t* __restrict__ W2, ushort_t* __restrict__ WO2,
        float* __restrict__ dwT){
    int i = blockIdx.x * 256 + threadIdx.x;           // 0..32767
    {
        int e = i & 7, ln = (i >> 3) & 63, ks = (i >> 9) & 3, of = i >> 11;
        W2[i] = f2bf(Win[(of*16 + (ln & 15))*128 + ks*32 + (ln >> 4)*8 + e]);
    }
    if (i < 16384){
        int e = i & 7, ln = (i >> 3) & 63, ks = (i >> 9) & 3, of = i >> 11;
        WO2[i] = f2bf(Wout[(of*16 + (ln & 15))*128 + ks*32 + (ln >> 4)*8 + e]);
    }
    if (i < 896){
        int j = i >> 7, c = i & 127;
        dwT[i] = dw_w[c*7 + j];
    }
}

// ---------------------------------------------------------------------------
// GEMM A: uv = W_in @ x + b_in, U = silu(uv[0:128]), V = uv[128:256].
// Output CHANNEL-major: UV[b][ch 0..255][L] bf16 (U = rows 0..127, V = 128..255).
// x fp32 staged -> bf16 token-major swizzled LDS -> MFMA -> ec LDS -> stores.
// grid(144,B) x 256.
// ---------------------------------------------------------------------------
__global__ __launch_bounds__(256) void k_gemmA(const float* __restrict__ x,
        const ushort_t* __restrict__ W2, const float* __restrict__ b_in,
        ushort_t* __restrict__ UV){
    __shared__ __align__(16) char unia[34816];          // xt fp32 [128][65] | ec
    float (*xt)[65] = (float(*)[65])unia;
    ushort_t* ec = (ushort_t*)unia;                     // [256][68]
    __shared__ __align__(16) ushort_t xtile[64 * 128];  // swizzled token-major

    const int b = blockIdx.y, l0 = blockIdx.x * 64, tid = threadIdx.x;
    const int wv = tid >> 6, lane = tid & 63;
    const int lo = lane & 15, hi = lane >> 4;

    #pragma unroll
    for (int k = 0; k < 32; ++k){
        int c = (tid >> 6) + k * 4;
        xt[c][lane] = x[((size_t)(b * 128 + c)) * LL + l0 + lane];
    }
    __syncthreads();
    #pragma unroll
    for (int p = 0; p < 16; ++p){
        int l = (tid >> 6) + p * 4;
        uint32 v = pack2(xt[2 * lane][l], xt[2 * lane + 1][l]);
        *(uint32*)((char*)xtile + l * 256 + ((lane * 4) ^ ((l & 7) << 4))) = v;
    }
    __syncthreads();

    const f32x4 zero = {0.f, 0.f, 0.f, 0.f};
    f32x4 acc[4][4];
    #pragma unroll
    for (int om = 0; om < 4; ++om)
        #pragma unroll
        for (int lf = 0; lf < 4; ++lf) acc[om][lf] = zero;

    #pragma unroll
    for (int ks = 0; ks < 4; ++ks){
        short8 af[4], bfr[4];
        #pragma unroll
        for (int om = 0; om < 4; ++om)
            af[om] = *(const short8*)(W2 + (size_t)(((wv*4 + om)*4 + ks)*64 + lane)*8);
        #pragma unroll
        for (int lf = 0; lf < 4; ++lf){
            int tok = lf * 16 + lo;
            bfr[lf] = *(const short8*)((char*)xtile + tok * 256 +
                        ((ks * 64 + hi * 16) ^ ((tok & 7) << 4)));
        }
        #pragma unroll
        for (int om = 0; om < 4; ++om)
            #pragma unroll
            for (int lf = 0; lf < 4; ++lf)
                acc[om][lf] = __builtin_amdgcn_mfma_f32_16x16x32_bf16(af[om], bfr[lf], acc[om][lf], 0, 0, 0);
    }
    __syncthreads();   // xt dead -> ec overlays

    #pragma unroll
    for (int om = 0; om < 4; ++om){
        int obase = wv * 64 + om * 16 + hi * 4;
        f32x4 bia = *(const f32x4*)(b_in + obase);
        const bool isU = (wv < 2);
        #pragma unroll
        for (int lf = 0; lf < 4; ++lf){
            #pragma unroll
            for (int r = 0; r < 4; ++r){
                float v = acc[om][lf][r] + bia[r];
                if (isU) v = silu_f(v);
                ec[(obase + r) * 68 + lf * 16 + lo] = f2bf(v);
            }
        }
    }
    __syncthreads();

    const int r8 = tid >> 5, c32 = tid & 31;
    #pragma unroll
    for (int p = 0; p < 32; ++p){
        int row = r8 + p * 8;                 // 0..255
        int col = c32 * 2;
        uint32 v = *(const uint32*)(ec + row * 68 + col);
        *(uint32*)(UV + ((size_t)(b * 256 + row)) * LL + l0 + col) = v;
    }
}

// ---------------------------------------------------------------------------
// Fused mixer + output GEMM, channel-major register-FIR.
// block 256 thr: cg = tid>>3 (32 chunks x 4ch), tg = tid&7 (8 groups x 8 tok).
// Each thread: 4 ch x 8 consecutive tokens. All tap data loaded ONCE via
// aligned contiguous short8 loads; taps extracted from registers (FIR).
// LN: shfl butterfly over wave's 8 cg + LDS cross-wave (2 barriers/pair).
// grid(144, B) x 256, XCD-chunked swizzle.
// ---------------------------------------------------------------------------
__global__ __launch_bounds__(256) void k_mixout(const ushort_t* __restrict__ UV,
        const float* __restrict__ dwT, const float* __restrict__ dw_b,
        const float* __restrict__ gamma, const float* __restrict__ beta,
        const ushort_t* __restrict__ WO2, const float* __restrict__ b_out,
        float* __restrict__ out){
    __shared__ __align__(16) float red2[4][64][6];      // padded rows (24 B)
    __shared__ __align__(16) float tot[64][4];
    __shared__ __align__(16) ushort_t ytile[64 * 128];  // swizzled

    // XCD-chunked swizzle: each XCD gets a contiguous run of 144 tiles
    const int flat = blockIdx.y * 144 + blockIdx.x;     // 0..1151
    const int nf = (flat & 7) * 144 + (flat >> 3);
    const int b  = nf / 144;
    const int m0 = (nf % 144) * 64;

    const int tid = threadIdx.x;
    const int lane = tid & 63;
    const int wv2 = tid >> 6;
    const int cg = tid >> 3;            // 0..31
    const int tg = tid & 7;
    const int c0 = cg * 4;
    const int m8 = m0 + tg * 8;
    const int h  = m8 / WW;             // uniform per thread (8 | 96)
    const int w0g = m8 - h * WW;

    const ushort_t* Ub = UV + ((size_t)(b * 256)) * LL;
    const ushort_t* Vb = UV + ((size_t)(b * 256 + 128)) * LL;

    // conv weights fp32 (per-lane, 4 ch)
    f32x4 cwv[7];
    #pragma unroll
    for (int j = 0; j < 7; ++j) cwv[j] = *(const f32x4*)(dwT + j * 128 + c0);
    const f32x4 biasv = *(const f32x4*)(dw_b + c0);

    // U (gate) packed bf16: 4 ch x 8 tok
    short8 u8[4];
    #pragma unroll
    for (int i = 0; i < 4; ++i)
        u8[i] = *(const short8*)(Ub + (size_t)(c0 + i) * LL + m8);

    // V center windows (also V-pair d=0 taps)
    short8 WBm[4];
    #pragma unroll
    for (int i = 0; i < 4; ++i)
        WBm[i] = *(const short8*)(Vb + (size_t)(c0 + i) * LL + m8);

    float ysr[4][8];
    #pragma unroll
    for (int ch = 0; ch < 4; ++ch)
        #pragma unroll
        for (int i = 0; i < 8; ++i) ysr[ch][i] = 0.f;

    const float inv = 1.f / 128.f;

    uint32 pky[4][8];

    auto reduce_apply = [&](float (&sa)[8], float (&qa)[8], float (&sb)[8], float (&qb)[8]){
        #pragma unroll
        for (int msk = 8; msk <= 32; msk <<= 1){
            #pragma unroll
            for (int i = 0; i < 8; ++i){
                sa[i] += __shfl_xor(sa[i], msk);
                qa[i] += __shfl_xor(qa[i], msk);
                sb[i] += __shfl_xor(sb[i], msk);
                qb[i] += __shfl_xor(qb[i], msk);
            }
        }
        const int cl = (lane >> 3) & 7;
        #pragma unroll
        for (int i = 0; i < 8; ++i){
            if (cl == i){
                int tok = tg * 8 + i;
                red2[wv2][tok][0] = sa[i];
                red2[wv2][tok][1] = qa[i];
                red2[wv2][tok][2] = sb[i];
                red2[wv2][tok][3] = qb[i];
            }
        }
        __syncthreads();
        {
            int tok = tid >> 2, st = tid & 3;
            tot[tok][st] = red2[0][tok][st] + red2[1][tok][st]
                         + red2[2][tok][st] + red2[3][tok][st];
        }
        __syncthreads();
        #pragma unroll
        for (int i = 0; i < 8; ++i){
            int tok = tg * 8 + i;
            f32x4 T = *(const f32x4*)(&tot[tok][0]);
            float mua = T[0] * inv, vara = T[1] * inv - mua * mua;
            float mub = T[2] * inv, varb = T[3] * inv - mub * mub;
            float ra = rsqrtf(vara + EPSF), rb = rsqrtf(varb + EPSF);
            #pragma unroll
            for (int ch = 0; ch < 4; ++ch){
                uint32 p = pky[ch][i];
                float ya = __uint_as_float(p << 16);
                float yb = __uint_as_float(p & 0xffff0000u);
                ysr[ch][i] += (ya - mua) * ra + (yb - mub) * rb;
            }
        }
    };

    // ================= PAIR 1: lr + rl (flat H taps, register FIR) ==========
    {
        float sa[8], qa[8], sb[8], qb[8];
        #pragma unroll
        for (int i = 0; i < 8; ++i){ sa[i]=0.f; qa[i]=0.f; sb[i]=0.f; qb[i]=0.f; }
        #pragma unroll
        for (int ch = 0; ch < 4; ++ch){
            const ushort_t* vrow = Vb + (size_t)(c0 + ch) * LL + m8;
            short8 WA = *(const short8*)(vrow - 8);
            short8 WC = *(const short8*)(vrow + 8);
            float f[14];
            #pragma unroll
            for (int k = 0; k < 14; ++k){
                int e = 5 + k;                 // elem m8-8+e = m8-3+k
                f[k] = bf2f(e < 8 ? WA[e] : (e < 16 ? WBm[ch][e - 8] : WC[e - 16]));
            }
            if (m8 == 0){ f[0] = 0.f; f[1] = 0.f; f[2] = 0.f; }
            if (m8 == LL - 8){ f[11] = 0.f; f[12] = 0.f; f[13] = 0.f; }
            #pragma unroll
            for (int i = 0; i < 8; ++i){
                float caf = biasv[ch], cbw = biasv[ch];
                #pragma unroll
                for (int j = 0; j < 7; ++j){
                    caf = fmaf(cwv[j][ch],     f[i + j], caf);
                    cbw = fmaf(cwv[6 - j][ch], f[i + j], cbw);
                }
                float uu = bf2f(u8[ch][i]);
                float ya = uu * silu_f(caf);
                float yb = uu * silu_f(cbw);
                sa[i] += ya; qa[i] += ya * ya; sb[i] += yb; qb[i] += yb * yb;
                pky[ch][i] = pack2(ya, yb);
            }
        }
        reduce_apply(sa, qa, sb, qb);
    }

    // ================= PAIR 2: tb + bt (vertical taps) ======================
    {
        float sa[8], qa[8], sb[8], qb[8];
        #pragma unroll
        for (int i = 0; i < 8; ++i){ sa[i]=0.f; qa[i]=0.f; sb[i]=0.f; qb[i]=0.f; }
        #pragma unroll
        for (int ch = 0; ch < 4; ++ch){
            const ushort_t* vrow = Vb + (size_t)(c0 + ch) * LL + m8;
            float caf[8], cbw[8];
            #pragma unroll
            for (int i = 0; i < 8; ++i){
                float v0 = bf2f(WBm[ch][i]);               // d = 0 tap
                caf[i] = fmaf(cwv[3][ch], v0, biasv[ch]);
                cbw[i] = fmaf(cwv[3][ch], v0, biasv[ch]);
            }
            #pragma unroll
            for (int r = 0; r < 6; ++r){
                const int dd = (r < 3) ? (r - 3) : (r - 2);
                const int j  = dd + 3;
                const int hd = h + dd;
                float gv[8];
                if (hd >= 0 && hd < HH){
                    short8 g8 = *(const short8*)(vrow + 96 * dd);
                    #pragma unroll
                    for (int i = 0; i < 8; ++i) gv[i] = bf2f(g8[i]);
                } else {
                    const int del = (hd < 0) ? (LL - 1) : (1 - LL);
                    #pragma unroll
                    for (int i = 0; i < 8; ++i){
                        int q = (w0g + i) * HH + hd;       // col-major flat pos
                        bool ok = (unsigned)q < (unsigned)LL;
                        gv[i] = ok ? bf2f(vrow[96 * dd + del + i]) : 0.f;
                    }
                }
                #pragma unroll
                for (int i = 0; i < 8; ++i){
                    caf[i] = fmaf(cwv[j][ch],     gv[i], caf[i]);
                    cbw[i] = fmaf(cwv[6 - j][ch], gv[i], cbw[i]);
                }
            }
            #pragma unroll
            for (int i = 0; i < 8; ++i){
                float uu = bf2f(u8[ch][i]);
                float ya = uu * silu_f(caf[i]);
                float yb = uu * silu_f(cbw[i]);
                sa[i] += ya; qa[i] += ya * ya; sb[i] += yb; qb[i] += yb * yb;
                pky[ch][i] = pack2(ya, yb);
            }
        }
        reduce_apply(sa, qa, sb, qb);
    }

    // ---- gamma/beta + pack to swizzled ytile -------------------------------
    {
        f32x4 gv4 = *(const f32x4*)(gamma + c0);
        f32x4 bv4 = *(const f32x4*)(beta + c0);
        #pragma unroll
        for (int i = 0; i < 8; ++i){
            int tok = tg * 8 + i;
            uint32 p0 = pack2(0.25f * gv4[0] * ysr[0][i] + bv4[0],
                              0.25f * gv4[1] * ysr[1][i] + bv4[1]);
            uint32 p1 = pack2(0.25f * gv4[2] * ysr[2][i] + bv4[2],
                              0.25f * gv4[3] * ysr[3][i] + bv4[3]);
            char* dst = (char*)ytile + tok * 256 + ((c0 * 2) ^ (i << 4));
            *(uint32*)dst = p0;
            *(uint32*)(dst + 4) = p1;
        }
    }
    __syncthreads();

    // ---- Phase 2: output GEMM from ytile -----------------------------------
    const int lo = lane & 15, hi = lane >> 4;
    const f32x4 zero = {0.f, 0.f, 0.f, 0.f};
    f32x4 acc[2][4];
    #pragma unroll
    for (int om = 0; om < 2; ++om)
        #pragma unroll
        for (int lf = 0; lf < 4; ++lf) acc[om][lf] = zero;

    #pragma unroll
    for (int ks = 0; ks < 4; ++ks){
        short8 af[2];
        #pragma unroll
        for (int om = 0; om < 2; ++om)
            af[om] = *(const short8*)(WO2 + (size_t)(((wv2*2 + om)*4 + ks)*64 + lane)*8);
        #pragma unroll
        for (int lf = 0; lf < 4; ++lf){
            int tok = lf * 16 + lo;
            short8 bfr = *(const short8*)((char*)ytile + tok * 256 +
                            ((ks * 64 + hi * 16) ^ ((tok & 7) << 4)));
            #pragma unroll
            for (int om = 0; om < 2; ++om)
                acc[om][lf] = __builtin_amdgcn_mfma_f32_16x16x32_bf16(af[om], bfr, acc[om][lf], 0, 0, 0);
        }
    }
    #pragma unroll
    for (int om = 0; om < 2; ++om){
        int ob = wv2 * 32 + om * 16 + hi * 4;
        f32x4 bia = *(const f32x4*)(b_out + ob);
        #pragma unroll
        for (int lf = 0; lf < 4; ++lf){
            #pragma unroll
            for (int r = 0; r < 4; ++r)
                out[((size_t)(b * 128 + ob + r)) * LL + m0 + lf * 16 + lo] = acc[om][lf][r] + bia[r];
        }
    }
}

// ---------------------------------------------------------------------------
extern "C" void kernel_launch(void* const* d_in, const int* in_sizes, int n_in,
                              void* d_out, int out_size, void* d_ws, size_t ws_size,
                              hipStream_t stream) {
    const float* x     = (const float*)d_in[0];
    const float* W_in  = (const float*)d_in[1];
    const float* b_in  = (const float*)d_in[2];
    const float* dw_w  = (const float*)d_in[3];
    const float* dw_b  = (const float*)d_in[4];
    const float* gamma = (const float*)d_in[5];
    const float* beta  = (const float*)d_in[6];
    const float* W_out = (const float*)d_in[7];
    const float* b_out = (const float*)d_in[8];
    float* out = (float*)d_out;

    // ws layout: UV (B,256,L) bf16 | 64B guard | W2 frag | WO2 frag | dwT
    ushort_t* UV  = (ushort_t*)d_ws;                       // 37,748,736 B
    ushort_t* W2  = UV + (size_t)BB * 256 * LL + 32;       // 256x128 bf16 frag
    ushort_t* WO2 = W2 + 256 * 128;                        // 128x128 bf16 frag
    float*    dwT = (float*)(WO2 + 128 * 128);             // [7][128] fp32

    k_prep<<<128, 256, 0, stream>>>(W_in, W_out, dw_w, W2, WO2, dwT);

    dim3 gA(LL / 64, BB);
    k_gemmA<<<gA, 256, 0, stream>>>(x, W2, b_in, UV);

    dim3 gM(LL / 64, BB);
    k_mixout<<<gM, 256, 0, stream>>>(UV, dwT, dw_b, gamma, beta,
                                     WO2, b_out, out);
}

// Round 8
// 112.404 us; speedup vs baseline: 1.3869x; 1.1998x over previous
//
#include <hip/hip_runtime.h>

#define BB 8
#define HH 96
#define WW 96
#define LL 9216
#define EPSF 1e-5f

typedef __attribute__((ext_vector_type(8))) short short8;
typedef __attribute__((ext_vector_type(4))) float f32x4;
typedef __attribute__((ext_vector_type(4))) unsigned int uint32x4;
typedef unsigned short ushort_t;
typedef unsigned int uint32;

__device__ __forceinline__ float silu_f(float x){ return x / (1.0f + __expf(-x)); }
__device__ __forceinline__ ushort_t f2bf(float f){
    uint32 u = __float_as_uint(f);
    u += 0x7FFFu + ((u >> 16) & 1u);          // RNE
    return (ushort_t)(u >> 16);
}
__device__ __forceinline__ float bf2f(short h){
    return __uint_as_float(((uint32)(ushort_t)h) << 16);
}
__device__ __forceinline__ uint32 pack2(float a, float b){
    return (uint32)f2bf(a) | ((uint32)f2bf(b) << 16);
}

// ---------------------------------------------------------------------------
// k_prep: W_in/W_out fp32 -> bf16 in MFMA A-fragment order
//   W2[((of*4+ks)*64 + lane)*8 + e] = W[of*16 + (lane&15)][ks*32 + (lane>>4)*8 + e]
// plus dwT[j][c] = dw_w[c][j] fp32.  grid 128 x 256.
// ---------------------------------------------------------------------------
__global__ __launch_bounds__(256) void k_prep(const float* __restrict__ Win,
        const float* __restrict__ Wout, const float* __restrict__ dw_w,
        ushort_t* __restrict__ W2, ushort_t* __restrict__ WO2,
        float* __restrict__ dwT){
    int i = blockIdx.x * 256 + threadIdx.x;           // 0..32767
    {
        int e = i & 7, ln = (i >> 3) & 63, ks = (i >> 9) & 3, of = i >> 11;
        W2[i] = f2bf(Win[(of*16 + (ln & 15))*128 + ks*32 + (ln >> 4)*8 + e]);
    }
    if (i < 16384){
        int e = i & 7, ln = (i >> 3) & 63, ks = (i >> 9) & 3, of = i >> 11;
        WO2[i] = f2bf(Wout[(of*16 + (ln & 15))*128 + ks*32 + (ln >> 4)*8 + e]);
    }
    if (i < 896){
        int j = i >> 7, c = i & 127;
        dwT[i] = dw_w[c*7 + j];
    }
}

// ---------------------------------------------------------------------------
// GEMM A: uv = W_in @ x + b_in, U = silu(uv[0:128]), V = uv[128:256].
// Output CHANNEL-major: UV[b][ch 0..255][L] bf16 (U = rows 0..127, V = 128..255).
// grid(144,B) x 256.   (unchanged from round 7 — passing)
// ---------------------------------------------------------------------------
__global__ __launch_bounds__(256) void k_gemmA(const float* __restrict__ x,
        const ushort_t* __restrict__ W2, const float* __restrict__ b_in,
        ushort_t* __restrict__ UV){
    __shared__ __align__(16) char unia[34816];          // xt fp32 [128][65] | ec
    float (*xt)[65] = (float(*)[65])unia;
    ushort_t* ec = (ushort_t*)unia;                     // [256][68]
    __shared__ __align__(16) ushort_t xtile[64 * 128];  // swizzled token-major

    const int b = blockIdx.y, l0 = blockIdx.x * 64, tid = threadIdx.x;
    const int wv = tid >> 6, lane = tid & 63;
    const int lo = lane & 15, hi = lane >> 4;

    #pragma unroll
    for (int k = 0; k < 32; ++k){
        int c = (tid >> 6) + k * 4;
        xt[c][lane] = x[((size_t)(b * 128 + c)) * LL + l0 + lane];
    }
    __syncthreads();
    #pragma unroll
    for (int p = 0; p < 16; ++p){
        int l = (tid >> 6) + p * 4;
        uint32 v = pack2(xt[2 * lane][l], xt[2 * lane + 1][l]);
        *(uint32*)((char*)xtile + l * 256 + ((lane * 4) ^ ((l & 7) << 4))) = v;
    }
    __syncthreads();

    const f32x4 zero = {0.f, 0.f, 0.f, 0.f};
    f32x4 acc[4][4];
    #pragma unroll
    for (int om = 0; om < 4; ++om)
        #pragma unroll
        for (int lf = 0; lf < 4; ++lf) acc[om][lf] = zero;

    #pragma unroll
    for (int ks = 0; ks < 4; ++ks){
        short8 af[4], bfr[4];
        #pragma unroll
        for (int om = 0; om < 4; ++om)
            af[om] = *(const short8*)(W2 + (size_t)(((wv*4 + om)*4 + ks)*64 + lane)*8);
        #pragma unroll
        for (int lf = 0; lf < 4; ++lf){
            int tok = lf * 16 + lo;
            bfr[lf] = *(const short8*)((char*)xtile + tok * 256 +
                        ((ks * 64 + hi * 16) ^ ((tok & 7) << 4)));
        }
        #pragma unroll
        for (int om = 0; om < 4; ++om)
            #pragma unroll
            for (int lf = 0; lf < 4; ++lf)
                acc[om][lf] = __builtin_amdgcn_mfma_f32_16x16x32_bf16(af[om], bfr[lf], acc[om][lf], 0, 0, 0);
    }
    __syncthreads();   // xt dead -> ec overlays

    #pragma unroll
    for (int om = 0; om < 4; ++om){
        int obase = wv * 64 + om * 16 + hi * 4;
        f32x4 bia = *(const f32x4*)(b_in + obase);
        const bool isU = (wv < 2);
        #pragma unroll
        for (int lf = 0; lf < 4; ++lf){
            #pragma unroll
            for (int r = 0; r < 4; ++r){
                float v = acc[om][lf][r] + bia[r];
                if (isU) v = silu_f(v);
                ec[(obase + r) * 68 + lf * 16 + lo] = f2bf(v);
            }
        }
    }
    __syncthreads();

    const int r8 = tid >> 5, c32 = tid & 31;
    #pragma unroll
    for (int p = 0; p < 32; ++p){
        int row = r8 + p * 8;                 // 0..255
        int col = c32 * 2;
        uint32 v = *(const uint32*)(ec + row * 68 + col);
        *(uint32*)(UV + ((size_t)(b * 256 + row)) * LL + l0 + col) = v;
    }
}

// ---------------------------------------------------------------------------
// transposing butterfly: reduce x[0..7] over lane bits 3..5; afterwards lane
// with cl=(lane>>3)&7 holds the total of x[cl].
// ---------------------------------------------------------------------------
__device__ __forceinline__ float tbfly8(float (&x)[8], int lane){
    const int t0 = (lane >> 3) & 1, t1 = (lane >> 4) & 1, t2 = (lane >> 5) & 1;
    float y[4], z[2];
    #pragma unroll
    for (int j = 0; j < 4; ++j){
        float keep = t0 ? x[2*j+1] : x[2*j];
        float send = t0 ? x[2*j]   : x[2*j+1];
        y[j] = keep + __shfl_xor(send, 8);
    }
    #pragma unroll
    for (int j = 0; j < 2; ++j){
        float keep = t1 ? y[2*j+1] : y[2*j];
        float send = t1 ? y[2*j]   : y[2*j+1];
        z[j] = keep + __shfl_xor(send, 16);
    }
    float keep = t2 ? z[1] : z[0];
    float send = t2 ? z[0] : z[1];
    return keep + __shfl_xor(send, 32);
}

// ---------------------------------------------------------------------------
// Fused mixer + output GEMM. 1024 thr = 16 waves; thread = 1 ch x 8 tokens.
// tg = lane&7 (token group), cl = (lane>>3)&7, c0 = wv*8+cl (channel).
// Register-FIR on channel-major V (each byte loaded once, contiguous).
// LN: transposing butterfly (in-wave, 8 ch) + red[16] LDS (cross-wave) +
// per-token mu/rsqrt computed once by 64 threads.
// grid(144, B) x 1024, XCD-chunked swizzle.
// ---------------------------------------------------------------------------
__global__ __launch_bounds__(1024, 4) void k_mixout(const ushort_t* __restrict__ UV,
        const float* __restrict__ dwT, const float* __restrict__ dw_b,
        const float* __restrict__ gamma, const float* __restrict__ beta,
        const ushort_t* __restrict__ WO2, const float* __restrict__ b_out,
        float* __restrict__ out){
    __shared__ __align__(16) float red[16][64][4];
    __shared__ float tot[64 * 5];
    __shared__ __align__(16) ushort_t ytile[64 * 128];

    // XCD-chunked swizzle
    const int flat = blockIdx.y * 144 + blockIdx.x;
    const int nf = (flat & 7) * 144 + (flat >> 3);
    const int b  = nf / 144;
    const int m0 = (nf % 144) * 64;

    const int tid  = threadIdx.x;
    const int lane = tid & 63;
    const int wv   = tid >> 6;           // 0..15
    const int tg   = lane & 7;
    const int cl   = (lane >> 3) & 7;
    const int c0   = wv * 8 + cl;        // channel 0..127
    const int m8   = m0 + tg * 8;
    const int h    = m8 / WW;            // uniform over the 8 tokens (8 | 96)
    const int w0g  = m8 - h * WW;

    const ushort_t* vrow = UV + ((size_t)(b * 256 + 128) + c0) * LL + m8;

    float cw[7];
    #pragma unroll
    for (int j = 0; j < 7; ++j) cw[j] = dwT[j * 128 + c0];
    const float bias = dw_b[c0];

    short8 u8  = *(const short8*)(UV + ((size_t)(b * 256) + c0) * LL + m8);
    short8 WBm = *(const short8*)(vrow);

    float ysr[8];
    #pragma unroll
    for (int i = 0; i < 8; ++i) ysr[i] = 0.f;
    uint32 pky[8];

    auto ln_round = [&](float (&sa)[8], float (&qa)[8], float (&sb)[8], float (&qb)[8]){
        float Sa = tbfly8(sa, lane), Qa = tbfly8(qa, lane);
        float Sb = tbfly8(sb, lane), Qb = tbfly8(qb, lane);
        const int tokw = tg * 8 + cl;
        f32x4 st = {Sa, Qa, Sb, Qb};
        *(f32x4*)(&red[wv][tokw][0]) = st;
        __syncthreads();
        if (tid < 64){
            float S0 = 0.f, Q0 = 0.f, S1 = 0.f, Q1 = 0.f;
            #pragma unroll
            for (int w2 = 0; w2 < 16; ++w2){
                f32x4 r4 = *(const f32x4*)(&red[w2][tid][0]);
                S0 += r4[0]; Q0 += r4[1]; S1 += r4[2]; Q1 += r4[3];
            }
            const float inv = 1.f / 128.f;
            float mua = S0 * inv, vara = Q0 * inv - mua * mua;
            float mub = S1 * inv, varb = Q1 * inv - mub * mub;
            tot[tid * 5 + 0] = mua; tot[tid * 5 + 1] = rsqrtf(vara + EPSF);
            tot[tid * 5 + 2] = mub; tot[tid * 5 + 3] = rsqrtf(varb + EPSF);
        }
        __syncthreads();
        #pragma unroll
        for (int i = 0; i < 8; ++i){
            int tok = tg * 8 + i;
            float mua = tot[tok * 5 + 0], ra = tot[tok * 5 + 1];
            float mub = tot[tok * 5 + 2], rb = tot[tok * 5 + 3];
            float ya = __uint_as_float(pky[i] << 16);
            float yb = __uint_as_float(pky[i] & 0xffff0000u);
            ysr[i] += (ya - mua) * ra + (yb - mub) * rb;
        }
    };

    // ================= PAIR 1: lr + rl (flat H taps, register FIR) ==========
    {
        short8 WA = *(const short8*)(vrow - 8);
        short8 WC = *(const short8*)(vrow + 8);
        float f[14];
        #pragma unroll
        for (int k = 0; k < 14; ++k){
            int e = 5 + k;                 // elem m8-8+e = m8-3+k
            f[k] = bf2f(e < 8 ? WA[e] : (e < 16 ? WBm[e - 8] : WC[e - 16]));
        }
        if (m8 == 0){ f[0] = 0.f; f[1] = 0.f; f[2] = 0.f; }
        if (m8 == LL - 8){ f[11] = 0.f; f[12] = 0.f; f[13] = 0.f; }
        float sa[8], qa[8], sb[8], qb[8];
        #pragma unroll
        for (int i = 0; i < 8; ++i){
            float caf = bias, cbw = bias;
            #pragma unroll
            for (int j = 0; j < 7; ++j){
                caf = fmaf(cw[j],     f[i + j], caf);
                cbw = fmaf(cw[6 - j], f[i + j], cbw);
            }
            float uu = bf2f(u8[i]);
            float ya = uu * silu_f(caf);
            float yb = uu * silu_f(cbw);
            pky[i] = pack2(ya, yb);
            sa[i] = ya; qa[i] = ya * ya; sb[i] = yb; qb[i] = yb * yb;
        }
        ln_round(sa, qa, sb, qb);
    }

    // ================= PAIR 2: tb + bt (vertical taps) ======================
    {
        float caf[8], cbw[8];
        #pragma unroll
        for (int i = 0; i < 8; ++i){
            float v0 = bf2f(WBm[i]);               // d = 0 tap
            caf[i] = fmaf(cw[3], v0, bias);
            cbw[i] = caf[i];
        }
        #pragma unroll
        for (int r = 0; r < 6; ++r){
            const int dd = (r < 3) ? (r - 3) : (r - 2);
            const int j  = dd + 3;
            const int hd = h + dd;
            float gv[8];
            if (hd >= 0 && hd < HH){
                short8 g8 = *(const short8*)(vrow + 96 * dd);
                #pragma unroll
                for (int i = 0; i < 8; ++i) gv[i] = bf2f(g8[i]);
            } else {
                const int del = (hd < 0) ? (LL - 1) : (1 - LL);
                #pragma unroll
                for (int i = 0; i < 8; ++i){
                    int q = (w0g + i) * HH + hd;   // col-major flat pos
                    bool ok = (unsigned)q < (unsigned)LL;
                    gv[i] = ok ? bf2f(vrow[96 * dd + del + i]) : 0.f;
                }
            }
            #pragma unroll
            for (int i = 0; i < 8; ++i){
                caf[i] = fmaf(cw[j],     gv[i], caf[i]);
                cbw[i] = fmaf(cw[6 - j], gv[i], cbw[i]);
            }
        }
        float sa[8], qa[8], sb[8], qb[8];
        #pragma unroll
        for (int i = 0; i < 8; ++i){
            float uu = bf2f(u8[i]);
            float ya = uu * silu_f(caf[i]);
            float yb = uu * silu_f(cbw[i]);
            pky[i] = pack2(ya, yb);
            sa[i] = ya; qa[i] = ya * ya; sb[i] = yb; qb[i] = yb * yb;
        }
        ln_round(sa, qa, sb, qb);
    }

    // ---- gamma/beta + 2B writes to swizzled ytile --------------------------
    {
        const float g  = gamma[c0];
        const float be = beta[c0];
        #pragma unroll
        for (int i = 0; i < 8; ++i){
            int tok = tg * 8 + i;
            int swz = ((tok & 7) ^ (tok >> 3)) << 4;
            ushort_t val = f2bf(0.25f * g * ysr[i] + be);
            *(ushort_t*)((char*)ytile + tok * 256 + ((c0 * 2) ^ swz)) = val;
        }
    }
    __syncthreads();

    // ---- Phase 2: output GEMM from ytile (16 waves: 8 o-frags x 4 l-frags) -
    const int lo = lane & 15, hi = lane >> 4;
    const int ow  = wv >> 1;             // 0..7: o-range [16*ow, 16*ow+16)
    const int lfb = (wv & 1) * 2;        // l-frag base: 0 or 2
    const f32x4 zero = {0.f, 0.f, 0.f, 0.f};
    f32x4 acc[2] = {zero, zero};
    #pragma unroll
    for (int ks = 0; ks < 4; ++ks){
        short8 af = *(const short8*)(WO2 + (size_t)((ow * 4 + ks) * 64 + lane) * 8);
        #pragma unroll
        for (int t2 = 0; t2 < 2; ++t2){
            int tok = (lfb + t2) * 16 + lo;
            int swz = ((tok & 7) ^ (tok >> 3)) << 4;
            short8 bfr = *(const short8*)((char*)ytile + tok * 256 +
                            ((ks * 64 + hi * 16) ^ swz));
            acc[t2] = __builtin_amdgcn_mfma_f32_16x16x32_bf16(af, bfr, acc[t2], 0, 0, 0);
        }
    }
    {
        f32x4 bia = *(const f32x4*)(b_out + ow * 16 + hi * 4);
        #pragma unroll
        for (int t2 = 0; t2 < 2; ++t2){
            int l = m0 + (lfb + t2) * 16 + lo;
            #pragma unroll
            for (int r = 0; r < 4; ++r){
                int o = ow * 16 + hi * 4 + r;
                out[((size_t)(b * 128 + o)) * LL + l] = acc[t2][r] + bia[r];
            }
        }
    }
}

// ---------------------------------------------------------------------------
extern "C" void kernel_launch(void* const* d_in, const int* in_sizes, int n_in,
                              void* d_out, int out_size, void* d_ws, size_t ws_size,
                              hipStream_t stream) {
    const float* x     = (const float*)d_in[0];
    const float* W_in  = (const float*)d_in[1];
    const float* b_in  = (const float*)d_in[2];
    const float* dw_w  = (const float*)d_in[3];
    const float* dw_b  = (const float*)d_in[4];
    const float* gamma = (const float*)d_in[5];
    const float* beta  = (const float*)d_in[6];
    const float* W_out = (const float*)d_in[7];
    const float* b_out = (const float*)d_in[8];
    float* out = (float*)d_out;

    // ws layout: UV (B,256,L) bf16 | 64B guard | W2 frag | WO2 frag | dwT
    ushort_t* UV  = (ushort_t*)d_ws;                       // 37,748,736 B
    ushort_t* W2  = UV + (size_t)BB * 256 * LL + 32;       // 256x128 bf16 frag
    ushort_t* WO2 = W2 + 256 * 128;                        // 128x128 bf16 frag
    float*    dwT = (float*)(WO2 + 128 * 128);             // [7][128] fp32

    k_prep<<<128, 256, 0, stream>>>(W_in, W_out, dw_w, W2, WO2, dwT);

    dim3 gA(LL / 64, BB);
    k_gemmA<<<gA, 256, 0, stream>>>(x, W2, b_in, UV);

    dim3 gM(144, BB);
    k_mixout<<<gM, 1024, 0, stream>>>(UV, dwT, dw_b, gamma, beta,
                                      WO2, b_out, out);
}

// Round 9
// 104.616 us; speedup vs baseline: 1.4902x; 1.0745x over previous
//
#include <hip/hip_runtime.h>

#define BB 8
#define HH 96
#define WW 96
#define LL 9216
#define EPSF 1e-5f

typedef __attribute__((ext_vector_type(8))) short short8;
typedef __attribute__((ext_vector_type(4))) float f32x4;
typedef __attribute__((ext_vector_type(2))) float f32x2;
typedef __attribute__((ext_vector_type(4))) unsigned int uint32x4;
typedef unsigned short ushort_t;
typedef unsigned int uint32;

// silu via v_rcp_f32 (full-precision fp32 div is ~11 inst without fast-math;
// rcp is 1 inst, ~1ulp -- invisible after bf16 rounding)
__device__ __forceinline__ float silu_f(float x){
    return x * __builtin_amdgcn_rcpf(1.0f + __expf(-x));
}
__device__ __forceinline__ ushort_t f2bf(float f){
    uint32 u = __float_as_uint(f);
    u += 0x7FFFu + ((u >> 16) & 1u);          // RNE
    return (ushort_t)(u >> 16);
}
__device__ __forceinline__ float bf2f(short h){
    return __uint_as_float(((uint32)(ushort_t)h) << 16);
}
__device__ __forceinline__ uint32 pack2(float a, float b){
    return (uint32)f2bf(a) | ((uint32)f2bf(b) << 16);
}

// ---------------------------------------------------------------------------
// k_prep: W_in/W_out fp32 -> bf16 in MFMA A-fragment order
//   W2[((of*4+ks)*64 + lane)*8 + e] = W[of*16 + (lane&15)][ks*32 + (lane>>4)*8 + e]
// plus dwT[j][c] = dw_w[c][j] fp32.  grid 128 x 256.
// ---------------------------------------------------------------------------
__global__ __launch_bounds__(256) void k_prep(const float* __restrict__ Win,
        const float* __restrict__ Wout, const float* __restrict__ dw_w,
        ushort_t* __restrict__ W2, ushort_t* __restrict__ WO2,
        float* __restrict__ dwT){
    int i = blockIdx.x * 256 + threadIdx.x;           // 0..32767
    {
        int e = i & 7, ln = (i >> 3) & 63, ks = (i >> 9) & 3, of = i >> 11;
        W2[i] = f2bf(Win[(of*16 + (ln & 15))*128 + ks*32 + (ln >> 4)*8 + e]);
    }
    if (i < 16384){
        int e = i & 7, ln = (i >> 3) & 63, ks = (i >> 9) & 3, of = i >> 11;
        WO2[i] = f2bf(Wout[(of*16 + (ln & 15))*128 + ks*32 + (ln >> 4)*8 + e]);
    }
    if (i < 896){
        int j = i >> 7, c = i & 127;
        dwT[i] = dw_w[c*7 + j];
    }
}

// ---------------------------------------------------------------------------
// GEMM A: uv = W_in @ x + b_in, U = silu(uv[0:128]), V = uv[128:256].
// Output CHANNEL-major: UV[b][ch 0..255][L] bf16 (U = rows 0..127, V = 128..255).
// grid(144,B) x 256.
// ---------------------------------------------------------------------------
__global__ __launch_bounds__(256) void k_gemmA(const float* __restrict__ x,
        const ushort_t* __restrict__ W2, const float* __restrict__ b_in,
        ushort_t* __restrict__ UV){
    __shared__ __align__(16) char unia[34816];          // xt fp32 [128][65] | ec
    float (*xt)[65] = (float(*)[65])unia;
    ushort_t* ec = (ushort_t*)unia;                     // [256][68]
    __shared__ __align__(16) ushort_t xtile[64 * 128];  // swizzled token-major

    const int b = blockIdx.y, l0 = blockIdx.x * 64, tid = threadIdx.x;
    const int wv = tid >> 6, lane = tid & 63;
    const int lo = lane & 15, hi = lane >> 4;

    #pragma unroll
    for (int k = 0; k < 32; ++k){
        int c = (tid >> 6) + k * 4;
        xt[c][lane] = x[((size_t)(b * 128 + c)) * LL + l0 + lane];
    }
    __syncthreads();
    #pragma unroll
    for (int p = 0; p < 16; ++p){
        int l = (tid >> 6) + p * 4;
        uint32 v = pack2(xt[2 * lane][l], xt[2 * lane + 1][l]);
        *(uint32*)((char*)xtile + l * 256 + ((lane * 4) ^ ((l & 7) << 4))) = v;
    }
    __syncthreads();

    const f32x4 zero = {0.f, 0.f, 0.f, 0.f};
    f32x4 acc[4][4];
    #pragma unroll
    for (int om = 0; om < 4; ++om)
        #pragma unroll
        for (int lf = 0; lf < 4; ++lf) acc[om][lf] = zero;

    #pragma unroll
    for (int ks = 0; ks < 4; ++ks){
        short8 af[4], bfr[4];
        #pragma unroll
        for (int om = 0; om < 4; ++om)
            af[om] = *(const short8*)(W2 + (size_t)(((wv*4 + om)*4 + ks)*64 + lane)*8);
        #pragma unroll
        for (int lf = 0; lf < 4; ++lf){
            int tok = lf * 16 + lo;
            bfr[lf] = *(const short8*)((char*)xtile + tok * 256 +
                        ((ks * 64 + hi * 16) ^ ((tok & 7) << 4)));
        }
        #pragma unroll
        for (int om = 0; om < 4; ++om)
            #pragma unroll
            for (int lf = 0; lf < 4; ++lf)
                acc[om][lf] = __builtin_amdgcn_mfma_f32_16x16x32_bf16(af[om], bfr[lf], acc[om][lf], 0, 0, 0);
    }
    __syncthreads();   // xt dead -> ec overlays

    #pragma unroll
    for (int om = 0; om < 4; ++om){
        int obase = wv * 64 + om * 16 + hi * 4;
        f32x4 bia = *(const f32x4*)(b_in + obase);
        const bool isU = (wv < 2);
        #pragma unroll
        for (int lf = 0; lf < 4; ++lf){
            #pragma unroll
            for (int r = 0; r < 4; ++r){
                float v = acc[om][lf][r] + bia[r];
                if (isU) v = silu_f(v);
                ec[(obase + r) * 68 + lf * 16 + lo] = f2bf(v);
            }
        }
    }
    __syncthreads();

    const int r8 = tid >> 5, c32 = tid & 31;
    #pragma unroll
    for (int p = 0; p < 32; ++p){
        int row = r8 + p * 8;                 // 0..255
        int col = c32 * 2;
        uint32 v = *(const uint32*)(ec + row * 68 + col);
        *(uint32*)(UV + ((size_t)(b * 256 + row)) * LL + l0 + col) = v;
    }
}

// ---------------------------------------------------------------------------
// transposing butterfly over lane bits 0..2: afterwards lane holds the total
// of x[lane & 7] (summed across the 8 lanes of its group).
// ---------------------------------------------------------------------------
__device__ __forceinline__ float tbfly8(float (&x)[8], int lane){
    const int t0 = lane & 1, t1 = (lane >> 1) & 1, t2 = (lane >> 2) & 1;
    float y[4], z[2];
    #pragma unroll
    for (int j = 0; j < 4; ++j){
        float keep = t0 ? x[2*j+1] : x[2*j];
        float send = t0 ? x[2*j]   : x[2*j+1];
        y[j] = keep + __shfl_xor(send, 1);
    }
    #pragma unroll
    for (int j = 0; j < 2; ++j){
        float keep = t1 ? y[2*j+1] : y[2*j];
        float send = t1 ? y[2*j]   : y[2*j+1];
        z[j] = keep + __shfl_xor(send, 2);
    }
    float keep = t2 ? z[1] : z[0];
    float send = t2 ? z[0] : z[1];
    return keep + __shfl_xor(send, 4);
}

// ---------------------------------------------------------------------------
// Fused mixer + output GEMM. 1024 thr = 16 waves; thread = 1 ch x 8 tokens.
// cl = lane&7 (channel-in-wave), tg = lane>>3 (token group), c0 = wv*8+cl.
// With this mapping the transposing butterfly (masks 1/2/4) leaves lane
// holding the total of token tg*8+(lane&7) == token[lane] -> red[wv][lane]
// f32x4 writes/reads are lane-consecutive = bank-conflict-free.
// grid(144, B) x 1024, XCD-chunked swizzle.
// ---------------------------------------------------------------------------
__global__ __launch_bounds__(1024, 4) void k_mixout(const ushort_t* __restrict__ UV,
        const float* __restrict__ dwT, const float* __restrict__ dw_b,
        const float* __restrict__ gamma, const float* __restrict__ beta,
        const ushort_t* __restrict__ WO2, const float* __restrict__ b_out,
        float* __restrict__ out){
    __shared__ __align__(16) float red[16][64][4];
    __shared__ float tot[64 * 6];
    __shared__ __align__(16) ushort_t ytile[64 * 128];

    // XCD-chunked swizzle
    const int flat = blockIdx.y * 144 + blockIdx.x;
    const int nf = (flat & 7) * 144 + (flat >> 3);
    const int b  = nf / 144;
    const int m0 = (nf % 144) * 64;

    const int tid  = threadIdx.x;
    const int lane = tid & 63;
    const int wv   = tid >> 6;           // 0..15
    const int cl   = lane & 7;
    const int tg   = lane >> 3;          // 0..7
    const int c0   = wv * 8 + cl;        // channel 0..127
    const int m8   = m0 + tg * 8;
    const int h    = m8 / WW;            // uniform over the 8 tokens (8 | 96)
    const int w0g  = m8 - h * WW;

    const ushort_t* vrow = UV + ((size_t)(b * 256 + 128) + c0) * LL + m8;

    float cw[7];
    #pragma unroll
    for (int j = 0; j < 7; ++j) cw[j] = dwT[j * 128 + c0];
    const float bias = dw_b[c0];

    short8 u8  = *(const short8*)(UV + ((size_t)(b * 256) + c0) * LL + m8);
    short8 WBm = *(const short8*)(vrow);

    float ysr[8];
    #pragma unroll
    for (int i = 0; i < 8; ++i) ysr[i] = 0.f;
    uint32 pky[8];

    auto ln_round = [&](float (&sa)[8], float (&qa)[8], float (&sb)[8], float (&qb)[8]){
        float Sa = tbfly8(sa, lane), Qa = tbfly8(qa, lane);
        float Sb = tbfly8(sb, lane), Qb = tbfly8(qb, lane);
        f32x4 st = {Sa, Qa, Sb, Qb};
        *(f32x4*)(&red[wv][lane][0]) = st;      // lane-consecutive: no conflicts
        __syncthreads();
        if (tid < 128){
            int token = tid >> 1, half = tid & 1;
            float S = 0.f, Q = 0.f;
            #pragma unroll
            for (int w2 = 0; w2 < 16; ++w2){
                f32x2 r2 = *(const f32x2*)(&red[w2][token][half * 2]);
                S += r2[0]; Q += r2[1];
            }
            const float inv = 1.f / 128.f;
            float mu = S * inv, var = Q * inv - mu * mu;
            tot[token * 6 + half * 2 + 0] = mu;
            tot[token * 6 + half * 2 + 1] = __builtin_amdgcn_rsqf(var + EPSF);
        }
        __syncthreads();
        #pragma unroll
        for (int i = 0; i < 8; ++i){
            int tok = tg * 8 + i;
            float mua = tot[tok * 6 + 0], ra = tot[tok * 6 + 1];
            float mub = tot[tok * 6 + 2], rb = tot[tok * 6 + 3];
            float ya = __uint_as_float(pky[i] << 16);
            float yb = __uint_as_float(pky[i] & 0xffff0000u);
            ysr[i] += (ya - mua) * ra + (yb - mub) * rb;
        }
    };

    // ================= PAIR 1: lr + rl (flat H taps, register FIR) ==========
    {
        short8 WA = *(const short8*)(vrow - 8);
        short8 WC = *(const short8*)(vrow + 8);
        float f[14];
        #pragma unroll
        for (int k = 0; k < 14; ++k){
            int e = 5 + k;                 // elem m8-8+e = m8-3+k
            f[k] = bf2f(e < 8 ? WA[e] : (e < 16 ? WBm[e - 8] : WC[e - 16]));
        }
        if (m8 == 0){ f[0] = 0.f; f[1] = 0.f; f[2] = 0.f; }
        if (m8 == LL - 8){ f[11] = 0.f; f[12] = 0.f; f[13] = 0.f; }
        float sa[8], qa[8], sb[8], qb[8];
        #pragma unroll
        for (int i = 0; i < 8; ++i){
            float caf = bias, cbw = bias;
            #pragma unroll
            for (int j = 0; j < 7; ++j){
                caf = fmaf(cw[j],     f[i + j], caf);
                cbw = fmaf(cw[6 - j], f[i + j], cbw);
            }
            float uu = bf2f(u8[i]);
            float ya = uu * silu_f(caf);
            float yb = uu * silu_f(cbw);
            pky[i] = pack2(ya, yb);
            sa[i] = ya; qa[i] = ya * ya; sb[i] = yb; qb[i] = yb * yb;
        }
        ln_round(sa, qa, sb, qb);
    }

    // ================= PAIR 2: tb + bt (vertical taps) ======================
    {
        float caf[8], cbw[8];
        #pragma unroll
        for (int i = 0; i < 8; ++i){
            float v0 = bf2f(WBm[i]);               // d = 0 tap
            caf[i] = fmaf(cw[3], v0, bias);
            cbw[i] = caf[i];
        }
        #pragma unroll
        for (int r = 0; r < 6; ++r){
            const int dd = (r < 3) ? (r - 3) : (r - 2);
            const int j  = dd + 3;
            const int hd = h + dd;
            float gv[8];
            if (hd >= 0 && hd < HH){
                short8 g8 = *(const short8*)(vrow + 96 * dd);
                #pragma unroll
                for (int i = 0; i < 8; ++i) gv[i] = bf2f(g8[i]);
            } else {
                const int del = (hd < 0) ? (LL - 1) : (1 - LL);
                #pragma unroll
                for (int i = 0; i < 8; ++i){
                    int q = (w0g + i) * HH + hd;   // col-major flat pos
                    bool ok = (unsigned)q < (unsigned)LL;
                    gv[i] = ok ? bf2f(vrow[96 * dd + del + i]) : 0.f;
                }
            }
            #pragma unroll
            for (int i = 0; i < 8; ++i){
                caf[i] = fmaf(cw[j],     gv[i], caf[i]);
                cbw[i] = fmaf(cw[6 - j], gv[i], cbw[i]);
            }
        }
        float sa[8], qa[8], sb[8], qb[8];
        #pragma unroll
        for (int i = 0; i < 8; ++i){
            float uu = bf2f(u8[i]);
            float ya = uu * silu_f(caf[i]);
            float yb = uu * silu_f(cbw[i]);
            pky[i] = pack2(ya, yb);
            sa[i] = ya; qa[i] = ya * ya; sb[i] = yb; qb[i] = yb * yb;
        }
        ln_round(sa, qa, sb, qb);
    }

    // ---- gamma/beta + 2B writes to swizzled ytile --------------------------
    {
        const float g  = gamma[c0];
        const float be = beta[c0];
        #pragma unroll
        for (int i = 0; i < 8; ++i){
            int tok = tg * 8 + i;
            int swz = ((tok & 7) ^ (tok >> 3)) << 4;
            ushort_t val = f2bf(0.25f * g * ysr[i] + be);
            *(ushort_t*)((char*)ytile + tok * 256 + ((c0 * 2) ^ swz)) = val;
        }
    }
    __syncthreads();

    // ---- Phase 2: output GEMM from ytile (16 waves: 8 o-frags x 4 l-frags) -
    const int lo = lane & 15, hi = lane >> 4;
    const int ow  = wv >> 1;             // 0..7: o-range [16*ow, 16*ow+16)
    const int lfb = (wv & 1) * 2;        // l-frag base: 0 or 2
    const f32x4 zero = {0.f, 0.f, 0.f, 0.f};
    f32x4 acc[2] = {zero, zero};
    #pragma unroll
    for (int ks = 0; ks < 4; ++ks){
        short8 af = *(const short8*)(WO2 + (size_t)((ow * 4 + ks) * 64 + lane) * 8);
        #pragma unroll
        for (int t2 = 0; t2 < 2; ++t2){
            int tok = (lfb + t2) * 16 + lo;
            int swz = ((tok & 7) ^ (tok >> 3)) << 4;
            short8 bfr = *(const short8*)((char*)ytile + tok * 256 +
                            ((ks * 64 + hi * 16) ^ swz));
            acc[t2] = __builtin_amdgcn_mfma_f32_16x16x32_bf16(af, bfr, acc[t2], 0, 0, 0);
        }
    }
    {
        f32x4 bia = *(const f32x4*)(b_out + ow * 16 + hi * 4);
        #pragma unroll
        for (int t2 = 0; t2 < 2; ++t2){
            int l = m0 + (lfb + t2) * 16 + lo;
            #pragma unroll
            for (int r = 0; r < 4; ++r){
                int o = ow * 16 + hi * 4 + r;
                out[((size_t)(b * 128 + o)) * LL + l] = acc[t2][r] + bia[r];
            }
        }
    }
}

// ---------------------------------------------------------------------------
extern "C" void kernel_launch(void* const* d_in, const int* in_sizes, int n_in,
                              void* d_out, int out_size, void* d_ws, size_t ws_size,
                              hipStream_t stream) {
    const float* x     = (const float*)d_in[0];
    const float* W_in  = (const float*)d_in[1];
    const float* b_in  = (const float*)d_in[2];
    const float* dw_w  = (const float*)d_in[3];
    const float* dw_b  = (const float*)d_in[4];
    const float* gamma = (const float*)d_in[5];
    const float* beta  = (const float*)d_in[6];
    const float* W_out = (const float*)d_in[7];
    const float* b_out = (const float*)d_in[8];
    float* out = (float*)d_out;

    // ws layout: UV (B,256,L) bf16 | 64B guard | W2 frag | WO2 frag | dwT
    ushort_t* UV  = (ushort_t*)d_ws;                       // 37,748,736 B
    ushort_t* W2  = UV + (size_t)BB * 256 * LL + 32;       // 256x128 bf16 frag
    ushort_t* WO2 = W2 + 256 * 128;                        // 128x128 bf16 frag
    float*    dwT = (float*)(WO2 + 128 * 128);             // [7][128] fp32

    k_prep<<<128, 256, 0, stream>>>(W_in, W_out, dw_w, W2, WO2, dwT);

    dim3 gA(LL / 64, BB);
    k_gemmA<<<gA, 256, 0, stream>>>(x, W2, b_in, UV);

    dim3 gM(144, BB);
    k_mixout<<<gM, 1024, 0, stream>>>(UV, dwT, dw_b, gamma, beta,
                                      WO2, b_out, out);
}

// Round 10
// 80.268 us; speedup vs baseline: 1.9422x; 1.3033x over previous
//
#include <hip/hip_runtime.h>

#define BB 8
#define HH 96
#define WW 96
#define LL 9216
#define EPSF 1e-5f

typedef __attribute__((ext_vector_type(8))) short short8;
typedef __attribute__((ext_vector_type(4))) float f32x4;
typedef __attribute__((ext_vector_type(2))) float f32x2;
typedef __attribute__((ext_vector_type(4))) unsigned int uint32x4;
typedef unsigned short ushort_t;
typedef unsigned int uint32;

// silu via v_rcp_f32 (fp32 div is ~11 inst without fast-math; rcp is 1 inst,
// ~1ulp -- invisible after bf16 rounding)
__device__ __forceinline__ float silu_f(float x){
    return x * __builtin_amdgcn_rcpf(1.0f + __expf(-x));
}
__device__ __forceinline__ ushort_t f2bf(float f){
    uint32 u = __float_as_uint(f);
    u += 0x7FFFu + ((u >> 16) & 1u);          // RNE
    return (ushort_t)(u >> 16);
}
__device__ __forceinline__ float bf2f(short h){
    return __uint_as_float(((uint32)(ushort_t)h) << 16);
}
__device__ __forceinline__ uint32 pack2(float a, float b){
    return (uint32)f2bf(a) | ((uint32)f2bf(b) << 16);
}

// ---------------------------------------------------------------------------
// k_prep: W_in/W_out fp32 -> bf16 in MFMA A-fragment order
//   W2[((of*4+ks)*64 + lane)*8 + e] = W[of*16 + (lane&15)][ks*32 + (lane>>4)*8 + e]
// plus dwT[j][c] = dw_w[c][j] fp32.  grid 128 x 256.
// ---------------------------------------------------------------------------
__global__ __launch_bounds__(256) void k_prep(const float* __restrict__ Win,
        const float* __restrict__ Wout, const float* __restrict__ dw_w,
        ushort_t* __restrict__ W2, ushort_t* __restrict__ WO2,
        float* __restrict__ dwT){
    int i = blockIdx.x * 256 + threadIdx.x;           // 0..32767
    {
        int e = i & 7, ln = (i >> 3) & 63, ks = (i >> 9) & 3, of = i >> 11;
        W2[i] = f2bf(Win[(of*16 + (ln & 15))*128 + ks*32 + (ln >> 4)*8 + e]);
    }
    if (i < 16384){
        int e = i & 7, ln = (i >> 3) & 63, ks = (i >> 9) & 3, of = i >> 11;
        WO2[i] = f2bf(Wout[(of*16 + (ln & 15))*128 + ks*32 + (ln >> 4)*8 + e]);
    }
    if (i < 896){
        int j = i >> 7, c = i & 127;
        dwT[i] = dw_w[c*7 + j];
    }
}

// ---------------------------------------------------------------------------
// GEMM A: uv = W_in @ x + b_in, U = silu(uv[0:128]), V = uv[128:256].
// Output CHANNEL-major: UV[b][ch 0..255][L] bf16 (U = rows 0..127, V = 128..255).
// grid(144,B) x 256.
// ---------------------------------------------------------------------------
__global__ __launch_bounds__(256) void k_gemmA(const float* __restrict__ x,
        const ushort_t* __restrict__ W2, const float* __restrict__ b_in,
        ushort_t* __restrict__ UV){
    __shared__ __align__(16) char unia[34816];          // xt fp32 [128][65] | ec
    float (*xt)[65] = (float(*)[65])unia;
    ushort_t* ec = (ushort_t*)unia;                     // [256][68]
    __shared__ __align__(16) ushort_t xtile[64 * 128];  // swizzled token-major

    const int b = blockIdx.y, l0 = blockIdx.x * 64, tid = threadIdx.x;
    const int wv = tid >> 6, lane = tid & 63;
    const int lo = lane & 15, hi = lane >> 4;

    #pragma unroll
    for (int k = 0; k < 32; ++k){
        int c = (tid >> 6) + k * 4;
        xt[c][lane] = x[((size_t)(b * 128 + c)) * LL + l0 + lane];
    }
    __syncthreads();
    #pragma unroll
    for (int p = 0; p < 16; ++p){
        int l = (tid >> 6) + p * 4;
        uint32 v = pack2(xt[2 * lane][l], xt[2 * lane + 1][l]);
        *(uint32*)((char*)xtile + l * 256 + ((lane * 4) ^ ((l & 7) << 4))) = v;
    }
    __syncthreads();

    const f32x4 zero = {0.f, 0.f, 0.f, 0.f};
    f32x4 acc[4][4];
    #pragma unroll
    for (int om = 0; om < 4; ++om)
        #pragma unroll
        for (int lf = 0; lf < 4; ++lf) acc[om][lf] = zero;

    #pragma unroll
    for (int ks = 0; ks < 4; ++ks){
        short8 af[4], bfr[4];
        #pragma unroll
        for (int om = 0; om < 4; ++om)
            af[om] = *(const short8*)(W2 + (size_t)(((wv*4 + om)*4 + ks)*64 + lane)*8);
        #pragma unroll
        for (int lf = 0; lf < 4; ++lf){
            int tok = lf * 16 + lo;
            bfr[lf] = *(const short8*)((char*)xtile + tok * 256 +
                        ((ks * 64 + hi * 16) ^ ((tok & 7) << 4)));
        }
        #pragma unroll
        for (int om = 0; om < 4; ++om)
            #pragma unroll
            for (int lf = 0; lf < 4; ++lf)
                acc[om][lf] = __builtin_amdgcn_mfma_f32_16x16x32_bf16(af[om], bfr[lf], acc[om][lf], 0, 0, 0);
    }
    __syncthreads();   // xt dead -> ec overlays

    #pragma unroll
    for (int om = 0; om < 4; ++om){
        int obase = wv * 64 + om * 16 + hi * 4;
        f32x4 bia = *(const f32x4*)(b_in + obase);
        const bool isU = (wv < 2);
        #pragma unroll
        for (int lf = 0; lf < 4; ++lf){
            #pragma unroll
            for (int r = 0; r < 4; ++r){
                float v = acc[om][lf][r] + bia[r];
                if (isU) v = silu_f(v);
                ec[(obase + r) * 68 + lf * 16 + lo] = f2bf(v);
            }
        }
    }
    __syncthreads();

    const int r8 = tid >> 5, c32 = tid & 31;
    #pragma unroll
    for (int p = 0; p < 32; ++p){
        int row = r8 + p * 8;                 // 0..255
        int col = c32 * 2;
        uint32 v = *(const uint32*)(ec + row * 68 + col);
        *(uint32*)(UV + ((size_t)(b * 256 + row)) * LL + l0 + col) = v;
    }
}

// ---------------------------------------------------------------------------
// transposing butterfly over lane bits 0..2: afterwards lane holds the total
// of x[lane & 7] over its 8-lane group.
// ---------------------------------------------------------------------------
__device__ __forceinline__ float tbfly8(float (&x)[8], int lane){
    const int t0 = lane & 1, t1 = (lane >> 1) & 1, t2 = (lane >> 2) & 1;
    float y[4], z[2];
    #pragma unroll
    for (int j = 0; j < 4; ++j){
        float keep = t0 ? x[2*j+1] : x[2*j];
        float send = t0 ? x[2*j]   : x[2*j+1];
        y[j] = keep + __shfl_xor(send, 1);
    }
    #pragma unroll
    for (int j = 0; j < 2; ++j){
        float keep = t1 ? y[2*j+1] : y[2*j];
        float send = t1 ? y[2*j]   : y[2*j+1];
        z[j] = keep + __shfl_xor(send, 2);
    }
    float keep = t2 ? z[1] : z[0];
    float send = t2 ? z[0] : z[1];
    return keep + __shfl_xor(send, 4);
}

// ---------------------------------------------------------------------------
// Fused mixer + output GEMM. 512 thr = 8 waves; 32-token tile.
// cl = lane&15 (ch-in-wave), tg = lane>>4 (0..3), c0 = wv*16+cl, m8 = m0+tg*8.
// All 10 tap loads issued upfront (no barrier before them). Both conv pairs
// computed, then ONE fused reduction: in-wave butterflies (masks 1/2/4 + 8),
// red[8][32][8] -> 1-wave serial stats -> apply all 4 dirs. 3 barriers total.
// grid(288, B) x 512, XCD-chunked swizzle.
// ---------------------------------------------------------------------------
__global__ __launch_bounds__(512, 4) void k_mixout(const ushort_t* __restrict__ UV,
        const float* __restrict__ dwT, const float* __restrict__ dw_b,
        const float* __restrict__ gamma, const float* __restrict__ beta,
        const ushort_t* __restrict__ WO2, const float* __restrict__ b_out,
        float* __restrict__ out){
    __shared__ __align__(16) float red[8][32][8];       // 8 KB
    __shared__ float tot[32 * 10];                      // 1.25 KB (stride 10)
    __shared__ __align__(16) ushort_t ytile[32 * 128];  // 8 KB swizzled

    // XCD-chunked swizzle over 2304 tiles
    const int flat = blockIdx.y * 288 + blockIdx.x;
    const int nf = (flat & 7) * 288 + (flat >> 3);
    const int b  = nf / 288;
    const int m0 = (nf % 288) * 32;

    const int tid  = threadIdx.x;
    const int lane = tid & 63;
    const int wv   = tid >> 6;           // 0..7
    const int cl   = lane & 15;
    const int tg   = lane >> 4;          // 0..3
    const int c0   = wv * 16 + cl;       // channel 0..127
    const int m8   = m0 + tg * 8;
    const int h    = m8 / WW;            // uniform over the 8 tokens
    const int w0g  = m8 - h * WW;

    const ushort_t* vrow = UV + ((size_t)(b * 256 + 128) + c0) * LL + m8;

    // ---- all global loads up front (latency hides under pair-1 compute) ----
    short8 u8  = *(const short8*)(UV + ((size_t)(b * 256) + c0) * LL + m8);
    short8 WBm = *(const short8*)(vrow);
    short8 WA  = *(const short8*)(vrow - 8);
    short8 WC  = *(const short8*)(vrow + 8);
    short8 g8[6];
    bool inb[6];
    #pragma unroll
    for (int r = 0; r < 6; ++r){
        const int dd = (r < 3) ? (r - 3) : (r - 2);
        const int hd = h + dd;
        inb[r] = (hd >= 0) && (hd < HH);
        g8[r] = *(const short8*)(vrow + 96 * dd);   // in-bounds of ws; gated by inb
    }
    float cw[7];
    #pragma unroll
    for (int j = 0; j < 7; ++j) cw[j] = dwT[j * 128 + c0];
    const float bias = dw_b[c0];

    uint32 pky1[8], pky2[8];
    float Sa, Qa, Sb, Qb, Sc, Qc, Sd, Qd;

    // ================= PAIR 1: lr + rl (flat H taps, register FIR) ==========
    {
        float f[14];
        #pragma unroll
        for (int k = 0; k < 14; ++k){
            int e = 5 + k;                 // elem m8-8+e = m8-3+k
            f[k] = bf2f(e < 8 ? WA[e] : (e < 16 ? WBm[e - 8] : WC[e - 16]));
        }
        if (m8 == 0){ f[0] = 0.f; f[1] = 0.f; f[2] = 0.f; }
        if (m8 == LL - 8){ f[11] = 0.f; f[12] = 0.f; f[13] = 0.f; }
        float sa[8], qa[8], sb[8], qb[8];
        #pragma unroll
        for (int i = 0; i < 8; ++i){
            float caf = bias, cbw = bias;
            #pragma unroll
            for (int j = 0; j < 7; ++j){
                caf = fmaf(cw[j],     f[i + j], caf);
                cbw = fmaf(cw[6 - j], f[i + j], cbw);
            }
            float uu = bf2f(u8[i]);
            float ya = uu * silu_f(caf);
            float yb = uu * silu_f(cbw);
            pky1[i] = pack2(ya, yb);
            sa[i] = ya; qa[i] = ya * ya; sb[i] = yb; qb[i] = yb * yb;
        }
        Sa = tbfly8(sa, lane); Sa += __shfl_xor(Sa, 8);
        Qa = tbfly8(qa, lane); Qa += __shfl_xor(Qa, 8);
        Sb = tbfly8(sb, lane); Sb += __shfl_xor(Sb, 8);
        Qb = tbfly8(qb, lane); Qb += __shfl_xor(Qb, 8);
    }

    // ================= PAIR 2: tb + bt (vertical taps) ======================
    {
        float caf[8], cbw[8];
        #pragma unroll
        for (int i = 0; i < 8; ++i){
            float v0 = bf2f(WBm[i]);               // d = 0 tap
            caf[i] = fmaf(cw[3], v0, bias);
            cbw[i] = caf[i];
        }
        #pragma unroll
        for (int r = 0; r < 6; ++r){
            const int dd = (r < 3) ? (r - 3) : (r - 2);
            const int j  = dd + 3;
            float gv[8];
            if (inb[r]){
                #pragma unroll
                for (int i = 0; i < 8; ++i) gv[i] = bf2f(g8[r][i]);
            } else {
                const int hd = h + dd;
                const int del = (hd < 0) ? (LL - 1) : (1 - LL);
                #pragma unroll
                for (int i = 0; i < 8; ++i){
                    int q = (w0g + i) * HH + hd;   // col-major flat pos
                    bool ok = (unsigned)q < (unsigned)LL;
                    gv[i] = ok ? bf2f(vrow[96 * dd + del + i]) : 0.f;
                }
            }
            #pragma unroll
            for (int i = 0; i < 8; ++i){
                caf[i] = fmaf(cw[j],     gv[i], caf[i]);
                cbw[i] = fmaf(cw[6 - j], gv[i], cbw[i]);
            }
        }
        float sa[8], qa[8], sb[8], qb[8];
        #pragma unroll
        for (int i = 0; i < 8; ++i){
            float uu = bf2f(u8[i]);
            float ya = uu * silu_f(caf[i]);
            float yb = uu * silu_f(cbw[i]);
            pky2[i] = pack2(ya, yb);
            sa[i] = ya; qa[i] = ya * ya; sb[i] = yb; qb[i] = yb * yb;
        }
        Sc = tbfly8(sa, lane); Sc += __shfl_xor(Sc, 8);
        Qc = tbfly8(qa, lane); Qc += __shfl_xor(Qc, 8);
        Sd = tbfly8(sb, lane); Sd += __shfl_xor(Sd, 8);
        Qd = tbfly8(qb, lane); Qd += __shfl_xor(Qd, 8);
    }

    // ---- single fused reduction --------------------------------------------
    {
        const int tok32 = tg * 8 + (lane & 7);
        const int halfp = (lane >> 3) & 1;       // duplicate lanes split halves
        f32x4 stv;
        if (halfp){ stv[0] = Sc; stv[1] = Qc; stv[2] = Sd; stv[3] = Qd; }
        else      { stv[0] = Sa; stv[1] = Qa; stv[2] = Sb; stv[3] = Qb; }
        *(f32x4*)(&red[wv][tok32][halfp * 4]) = stv;
    }
    __syncthreads();
    if (tid < 64){
        int token = tid >> 1, d2 = tid & 1;
        f32x4 s = {0.f, 0.f, 0.f, 0.f};
        #pragma unroll
        for (int w2 = 0; w2 < 8; ++w2)
            s += *(const f32x4*)(&red[w2][token][d2 * 4]);
        const float inv = 1.f / 128.f;
        float mu0 = s[0] * inv, r0 = __builtin_amdgcn_rsqf(s[1] * inv - mu0 * mu0 + EPSF);
        float mu1 = s[2] * inv, r1 = __builtin_amdgcn_rsqf(s[3] * inv - mu1 * mu1 + EPSF);
        f32x2 w0 = {mu0, r0}, w1 = {mu1, r1};
        *(f32x2*)(&tot[token * 10 + d2 * 4])     = w0;
        *(f32x2*)(&tot[token * 10 + d2 * 4 + 2]) = w1;
    }
    __syncthreads();

    // ---- apply all 4 dirs + gamma/beta + ytile -----------------------------
    {
        const float g  = gamma[c0];
        const float be = beta[c0];
        #pragma unroll
        for (int i = 0; i < 8; ++i){
            int tok = tg * 8 + i;
            f32x2 ta = *(const f32x2*)(&tot[tok * 10 + 0]);
            f32x2 tb = *(const f32x2*)(&tot[tok * 10 + 2]);
            f32x2 tc = *(const f32x2*)(&tot[tok * 10 + 4]);
            f32x2 td = *(const f32x2*)(&tot[tok * 10 + 6]);
            float ya = __uint_as_float(pky1[i] << 16);
            float yb = __uint_as_float(pky1[i] & 0xffff0000u);
            float yc = __uint_as_float(pky2[i] << 16);
            float yd = __uint_as_float(pky2[i] & 0xffff0000u);
            float ysr = (ya - ta[0]) * ta[1] + (yb - tb[0]) * tb[1]
                      + (yc - tc[0]) * tc[1] + (yd - td[0]) * td[1];
            int swz = ((tok & 7) ^ (tok >> 3)) << 4;
            *(ushort_t*)((char*)ytile + tok * 256 + ((c0 * 2) ^ swz)) =
                f2bf(0.25f * g * ysr + be);
        }
    }
    __syncthreads();

    // ---- Phase 2: output GEMM (8 waves: wave = 16-o frag x 32 tok) ---------
    const int lo = lane & 15, hi = lane >> 4;
    const int ow = wv;                    // o-range [16*ow, 16*ow+16)
    const f32x4 zero = {0.f, 0.f, 0.f, 0.f};
    f32x4 acc[2] = {zero, zero};
    #pragma unroll
    for (int ks = 0; ks < 4; ++ks){
        short8 af = *(const short8*)(WO2 + (size_t)((ow * 4 + ks) * 64 + lane) * 8);
        #pragma unroll
        for (int t2 = 0; t2 < 2; ++t2){
            int tok = t2 * 16 + lo;
            int swz = ((tok & 7) ^ (tok >> 3)) << 4;
            short8 bfr = *(const short8*)((char*)ytile + tok * 256 +
                            ((ks * 64 + hi * 16) ^ swz));
            acc[t2] = __builtin_amdgcn_mfma_f32_16x16x32_bf16(af, bfr, acc[t2], 0, 0, 0);
        }
    }
    {
        f32x4 bia = *(const f32x4*)(b_out + ow * 16 + hi * 4);
        #pragma unroll
        for (int t2 = 0; t2 < 2; ++t2){
            int l = m0 + t2 * 16 + lo;
            #pragma unroll
            for (int r = 0; r < 4; ++r){
                int o = ow * 16 + hi * 4 + r;
                out[((size_t)(b * 128 + o)) * LL + l] = acc[t2][r] + bia[r];
            }
        }
    }
}

// ---------------------------------------------------------------------------
extern "C" void kernel_launch(void* const* d_in, const int* in_sizes, int n_in,
                              void* d_out, int out_size, void* d_ws, size_t ws_size,
                              hipStream_t stream) {
    const float* x     = (const float*)d_in[0];
    const float* W_in  = (const float*)d_in[1];
    const float* b_in  = (const float*)d_in[2];
    const float* dw_w  = (const float*)d_in[3];
    const float* dw_b  = (const float*)d_in[4];
    const float* gamma = (const float*)d_in[5];
    const float* beta  = (const float*)d_in[6];
    const float* W_out = (const float*)d_in[7];
    const float* b_out = (const float*)d_in[8];
    float* out = (float*)d_out;

    // ws layout: UV (B,256,L) bf16 | 64B guard | W2 frag | WO2 frag | dwT
    ushort_t* UV  = (ushort_t*)d_ws;                       // 37,748,736 B
    ushort_t* W2  = UV + (size_t)BB * 256 * LL + 32;       // 256x128 bf16 frag
    ushort_t* WO2 = W2 + 256 * 128;                        // 128x128 bf16 frag
    float*    dwT = (float*)(WO2 + 128 * 128);             // [7][128] fp32

    k_prep<<<128, 256, 0, stream>>>(W_in, W_out, dw_w, W2, WO2, dwT);

    dim3 gA(LL / 64, BB);
    k_gemmA<<<gA, 256, 0, stream>>>(x, W2, b_in, UV);

    dim3 gM(288, BB);
    k_mixout<<<gM, 512, 0, stream>>>(UV, dwT, dw_b, gamma, beta,
                                     WO2, b_out, out);
}

// Round 11
// 77.864 us; speedup vs baseline: 2.0022x; 1.0309x over previous
//
#include <hip/hip_runtime.h>

#define BB 8
#define HH 96
#define WW 96
#define LL 9216
#define EPSF 1e-5f

typedef __attribute__((ext_vector_type(8))) short short8;
typedef __attribute__((ext_vector_type(4))) float f32x4;
typedef __attribute__((ext_vector_type(2))) float f32x2;
typedef __attribute__((ext_vector_type(4))) unsigned int uint32x4;
typedef unsigned short ushort_t;
typedef unsigned int uint32;

// silu via v_rcp_f32 (fp32 div is ~11 inst without fast-math; rcp is 1 inst,
// ~1ulp -- invisible after bf16 rounding)
__device__ __forceinline__ float silu_f(float x){
    return x * __builtin_amdgcn_rcpf(1.0f + __expf(-x));
}
__device__ __forceinline__ ushort_t f2bf(float f){
    uint32 u = __float_as_uint(f);
    u += 0x7FFFu + ((u >> 16) & 1u);          // RNE
    return (ushort_t)(u >> 16);
}
__device__ __forceinline__ float bf2f(short h){
    return __uint_as_float(((uint32)(ushort_t)h) << 16);
}
__device__ __forceinline__ uint32 pack2(float a, float b){
    return (uint32)f2bf(a) | ((uint32)f2bf(b) << 16);
}

// ---------------------------------------------------------------------------
// k_prep: W_in/W_out fp32 -> bf16 in MFMA A-fragment order
//   W2[((of*4+ks)*64 + lane)*8 + e] = W[of*16 + (lane&15)][ks*32 + (lane>>4)*8 + e]
// plus dwT[j][c] = dw_w[c][j] fp32.  grid 128 x 256.
// ---------------------------------------------------------------------------
__global__ __launch_bounds__(256) void k_prep(const float* __restrict__ Win,
        const float* __restrict__ Wout, const float* __restrict__ dw_w,
        ushort_t* __restrict__ W2, ushort_t* __restrict__ WO2,
        float* __restrict__ dwT){
    int i = blockIdx.x * 256 + threadIdx.x;           // 0..32767
    {
        int e = i & 7, ln = (i >> 3) & 63, ks = (i >> 9) & 3, of = i >> 11;
        W2[i] = f2bf(Win[(of*16 + (ln & 15))*128 + ks*32 + (ln >> 4)*8 + e]);
    }
    if (i < 16384){
        int e = i & 7, ln = (i >> 3) & 63, ks = (i >> 9) & 3, of = i >> 11;
        WO2[i] = f2bf(Wout[(of*16 + (ln & 15))*128 + ks*32 + (ln >> 4)*8 + e]);
    }
    if (i < 896){
        int j = i >> 7, c = i & 127;
        dwT[i] = dw_w[c*7 + j];
    }
}

// ---------------------------------------------------------------------------
// GEMM A: uv = W_in @ x + b_in, U = silu(uv[0:128]), V = uv[128:256].
// Output CHANNEL-major: UV[b][ch 0..255][L] bf16 (U = rows 0..127, V = 128..255).
// grid(144,B) x 256.
// ---------------------------------------------------------------------------
__global__ __launch_bounds__(256) void k_gemmA(const float* __restrict__ x,
        const ushort_t* __restrict__ W2, const float* __restrict__ b_in,
        ushort_t* __restrict__ UV){
    __shared__ __align__(16) char unia[34816];          // xt fp32 [128][65] | ec
    float (*xt)[65] = (float(*)[65])unia;
    ushort_t* ec = (ushort_t*)unia;                     // [256][68]
    __shared__ __align__(16) ushort_t xtile[64 * 128];  // swizzled token-major

    const int b = blockIdx.y, l0 = blockIdx.x * 64, tid = threadIdx.x;
    const int wv = tid >> 6, lane = tid & 63;
    const int lo = lane & 15, hi = lane >> 4;

    #pragma unroll
    for (int k = 0; k < 32; ++k){
        int c = (tid >> 6) + k * 4;
        xt[c][lane] = x[((size_t)(b * 128 + c)) * LL + l0 + lane];
    }
    __syncthreads();
    #pragma unroll
    for (int p = 0; p < 16; ++p){
        int l = (tid >> 6) + p * 4;
        uint32 v = pack2(xt[2 * lane][l], xt[2 * lane + 1][l]);
        *(uint32*)((char*)xtile + l * 256 + ((lane * 4) ^ ((l & 7) << 4))) = v;
    }
    __syncthreads();

    const f32x4 zero = {0.f, 0.f, 0.f, 0.f};
    f32x4 acc[4][4];
    #pragma unroll
    for (int om = 0; om < 4; ++om)
        #pragma unroll
        for (int lf = 0; lf < 4; ++lf) acc[om][lf] = zero;

    #pragma unroll
    for (int ks = 0; ks < 4; ++ks){
        short8 af[4], bfr[4];
        #pragma unroll
        for (int om = 0; om < 4; ++om)
            af[om] = *(const short8*)(W2 + (size_t)(((wv*4 + om)*4 + ks)*64 + lane)*8);
        #pragma unroll
        for (int lf = 0; lf < 4; ++lf){
            int tok = lf * 16 + lo;
            bfr[lf] = *(const short8*)((char*)xtile + tok * 256 +
                        ((ks * 64 + hi * 16) ^ ((tok & 7) << 4)));
        }
        #pragma unroll
        for (int om = 0; om < 4; ++om)
            #pragma unroll
            for (int lf = 0; lf < 4; ++lf)
                acc[om][lf] = __builtin_amdgcn_mfma_f32_16x16x32_bf16(af[om], bfr[lf], acc[om][lf], 0, 0, 0);
    }
    __syncthreads();   // xt dead -> ec overlays

    #pragma unroll
    for (int om = 0; om < 4; ++om){
        int obase = wv * 64 + om * 16 + hi * 4;
        f32x4 bia = *(const f32x4*)(b_in + obase);
        const bool isU = (wv < 2);
        #pragma unroll
        for (int lf = 0; lf < 4; ++lf){
            #pragma unroll
            for (int r = 0; r < 4; ++r){
                float v = acc[om][lf][r] + bia[r];
                if (isU) v = silu_f(v);
                ec[(obase + r) * 68 + lf * 16 + lo] = f2bf(v);
            }
        }
    }
    __syncthreads();

    const int r8 = tid >> 5, c32 = tid & 31;
    #pragma unroll
    for (int p = 0; p < 32; ++p){
        int row = r8 + p * 8;                 // 0..255
        int col = c32 * 2;
        uint32 v = *(const uint32*)(ec + row * 68 + col);
        *(uint32*)(UV + ((size_t)(b * 256 + row)) * LL + l0 + col) = v;
    }
}

// ---------------------------------------------------------------------------
// transposing butterfly over lane bits 0..2: afterwards lane holds the total
// of x[lane & 7] over its 8-lane group.
// ---------------------------------------------------------------------------
__device__ __forceinline__ float tbfly8(float (&x)[8], int lane){
    const int t0 = lane & 1, t1 = (lane >> 1) & 1, t2 = (lane >> 2) & 1;
    float y[4], z[2];
    #pragma unroll
    for (int j = 0; j < 4; ++j){
        float keep = t0 ? x[2*j+1] : x[2*j];
        float send = t0 ? x[2*j]   : x[2*j+1];
        y[j] = keep + __shfl_xor(send, 1);
    }
    #pragma unroll
    for (int j = 0; j < 2; ++j){
        float keep = t1 ? y[2*j+1] : y[2*j];
        float send = t1 ? y[2*j]   : y[2*j+1];
        z[j] = keep + __shfl_xor(send, 2);
    }
    float keep = t2 ? z[1] : z[0];
    float send = t2 ? z[0] : z[1];
    return keep + __shfl_xor(send, 4);
}

// ---------------------------------------------------------------------------
// Fused mixer + output GEMM. 512 thr = 8 waves; 32-token tile.
// cl = lane&15 (ch-in-wave), tg = lane>>4 (0..3), c0 = wv*16+cl, m8 = m0+tg*8.
// All tap loads upfront; both conv pairs in fp32 registers (no bf16 pack);
// ONE fused reduction; apply = sum_d y_d*r_d - C (C precomputed per token).
// ytile rows 288B (bank rotation), red rows 12 floats. 3 barriers total.
// grid(288, B) x 512, XCD-chunked swizzle.
// ---------------------------------------------------------------------------
__global__ __launch_bounds__(512, 4) void k_mixout(const ushort_t* __restrict__ UV,
        const float* __restrict__ dwT, const float* __restrict__ dw_b,
        const float* __restrict__ gamma, const float* __restrict__ beta,
        const ushort_t* __restrict__ WO2, const float* __restrict__ b_out,
        float* __restrict__ out){
    __shared__ __align__(16) float red[8][32][12];      // 12 KB (48B rows)
    __shared__ float tot[32 * 6];                       // ra,rb,rc,rd,C per tok
    __shared__ __align__(16) char ytile[32 * 288];      // 9 KB, 288B rows

    // XCD-chunked swizzle over 2304 tiles
    const int flat = blockIdx.y * 288 + blockIdx.x;
    const int nf = (flat & 7) * 288 + (flat >> 3);
    const int b  = nf / 288;
    const int m0 = (nf % 288) * 32;

    const int tid  = threadIdx.x;
    const int lane = tid & 63;
    const int wv   = tid >> 6;           // 0..7
    const int cl   = lane & 15;
    const int tg   = lane >> 4;          // 0..3
    const int c0   = wv * 16 + cl;       // channel 0..127
    const int m8   = m0 + tg * 8;
    const int h    = m8 / WW;            // uniform over the 8 tokens
    const int w0g  = m8 - h * WW;

    const ushort_t* vrow = UV + ((size_t)(b * 256 + 128) + c0) * LL + m8;

    // ---- all global loads up front (latency hides under pair-1 compute) ----
    short8 u8  = *(const short8*)(UV + ((size_t)(b * 256) + c0) * LL + m8);
    short8 WBm = *(const short8*)(vrow);
    short8 WA  = *(const short8*)(vrow - 8);
    short8 WC  = *(const short8*)(vrow + 8);
    short8 g8[6];
    bool inb[6];
    #pragma unroll
    for (int r = 0; r < 6; ++r){
        const int dd = (r < 3) ? (r - 3) : (r - 2);
        const int hd = h + dd;
        inb[r] = (hd >= 0) && (hd < HH);
        g8[r] = *(const short8*)(vrow + 96 * dd);   // in ws bounds; gated by inb
    }
    float cw[7];
    #pragma unroll
    for (int j = 0; j < 7; ++j) cw[j] = dwT[j * 128 + c0];
    const float bias = dw_b[c0];

    float ya[8], yb[8], yc[8], yd[8];    // 4 directions, fp32 (no pack)
    float Sa, Qa, Sb, Qb, Sc, Qc, Sd, Qd;

    // ================= PAIR 1: lr + rl (flat H taps, register FIR) ==========
    {
        float f[14];
        #pragma unroll
        for (int k = 0; k < 14; ++k){
            int e = 5 + k;                 // elem m8-8+e = m8-3+k
            f[k] = bf2f(e < 8 ? WA[e] : (e < 16 ? WBm[e - 8] : WC[e - 16]));
        }
        if (m8 == 0){ f[0] = 0.f; f[1] = 0.f; f[2] = 0.f; }
        if (m8 == LL - 8){ f[11] = 0.f; f[12] = 0.f; f[13] = 0.f; }
        float qa[8], qb[8];
        #pragma unroll
        for (int i = 0; i < 8; ++i){
            float caf = bias, cbw = bias;
            #pragma unroll
            for (int j = 0; j < 7; ++j){
                caf = fmaf(cw[j],     f[i + j], caf);
                cbw = fmaf(cw[6 - j], f[i + j], cbw);
            }
            float uu = bf2f(u8[i]);
            ya[i] = uu * silu_f(caf);
            yb[i] = uu * silu_f(cbw);
            qa[i] = ya[i] * ya[i];
            qb[i] = yb[i] * yb[i];
        }
        Sa = tbfly8(ya, lane); Sa += __shfl_xor(Sa, 8);
        Qa = tbfly8(qa, lane); Qa += __shfl_xor(Qa, 8);
        Sb = tbfly8(yb, lane); Sb += __shfl_xor(Sb, 8);
        Qb = tbfly8(qb, lane); Qb += __shfl_xor(Qb, 8);
    }

    // ================= PAIR 2: tb + bt (vertical taps) ======================
    {
        float caf[8], cbw[8];
        #pragma unroll
        for (int i = 0; i < 8; ++i){
            float v0 = bf2f(WBm[i]);               // d = 0 tap
            caf[i] = fmaf(cw[3], v0, bias);
            cbw[i] = caf[i];
        }
        #pragma unroll
        for (int r = 0; r < 6; ++r){
            const int dd = (r < 3) ? (r - 3) : (r - 2);
            const int j  = dd + 3;
            float gv[8];
            if (inb[r]){
                #pragma unroll
                for (int i = 0; i < 8; ++i) gv[i] = bf2f(g8[r][i]);
            } else {
                const int hd = h + dd;
                const int del = (hd < 0) ? (LL - 1) : (1 - LL);
                #pragma unroll
                for (int i = 0; i < 8; ++i){
                    int q = (w0g + i) * HH + hd;   // col-major flat pos
                    bool ok = (unsigned)q < (unsigned)LL;
                    gv[i] = ok ? bf2f(vrow[96 * dd + del + i]) : 0.f;
                }
            }
            #pragma unroll
            for (int i = 0; i < 8; ++i){
                caf[i] = fmaf(cw[j],     gv[i], caf[i]);
                cbw[i] = fmaf(cw[6 - j], gv[i], cbw[i]);
            }
        }
        float qc[8], qd[8];
        #pragma unroll
        for (int i = 0; i < 8; ++i){
            float uu = bf2f(u8[i]);
            yc[i] = uu * silu_f(caf[i]);
            yd[i] = uu * silu_f(cbw[i]);
            qc[i] = yc[i] * yc[i];
            qd[i] = yd[i] * yd[i];
        }
        Sc = tbfly8(yc, lane); Sc += __shfl_xor(Sc, 8);
        Qc = tbfly8(qc, lane); Qc += __shfl_xor(Qc, 8);
        Sd = tbfly8(yd, lane); Sd += __shfl_xor(Sd, 8);
        Qd = tbfly8(qd, lane); Qd += __shfl_xor(Qd, 8);
    }

    // ---- single fused reduction --------------------------------------------
    {
        const int tok32 = tg * 8 + (lane & 7);
        const int halfp = (lane >> 3) & 1;       // duplicate lanes split pairs
        f32x4 stv;
        if (halfp){ stv[0] = Sc; stv[1] = Qc; stv[2] = Sd; stv[3] = Qd; }
        else      { stv[0] = Sa; stv[1] = Qa; stv[2] = Sb; stv[3] = Qb; }
        *(f32x4*)(&red[wv][tok32][halfp * 4]) = stv;
    }
    __syncthreads();
    if (tid < 32){
        f32x4 s0 = {0.f, 0.f, 0.f, 0.f}, s1 = {0.f, 0.f, 0.f, 0.f};
        #pragma unroll
        for (int w2 = 0; w2 < 8; ++w2){
            s0 += *(const f32x4*)(&red[w2][tid][0]);
            s1 += *(const f32x4*)(&red[w2][tid][4]);
        }
        const float inv = 1.f / 128.f;
        float mua = s0[0] * inv, ra = __builtin_amdgcn_rsqf(s0[1] * inv - mua * mua + EPSF);
        float mub = s0[2] * inv, rb = __builtin_amdgcn_rsqf(s0[3] * inv - mub * mub + EPSF);
        float muc = s1[0] * inv, rc = __builtin_amdgcn_rsqf(s1[1] * inv - muc * muc + EPSF);
        float mud = s1[2] * inv, rd = __builtin_amdgcn_rsqf(s1[3] * inv - mud * mud + EPSF);
        float C = mua * ra + mub * rb + muc * rc + mud * rd;
        tot[tid * 6 + 0] = ra; tot[tid * 6 + 1] = rb;
        tot[tid * 6 + 2] = rc; tot[tid * 6 + 3] = rd;
        tot[tid * 6 + 4] = C;
    }
    __syncthreads();

    // ---- apply all 4 dirs + gamma/beta + ytile -----------------------------
    {
        const float g4 = 0.25f * gamma[c0];
        const float be = beta[c0];
        #pragma unroll
        for (int i = 0; i < 8; ++i){
            int tok = tg * 8 + i;
            f32x2 r01 = *(const f32x2*)(&tot[tok * 6 + 0]);
            f32x2 r23 = *(const f32x2*)(&tot[tok * 6 + 2]);
            float C   = tot[tok * 6 + 4];
            float v = fmaf(ya[i], r01[0], fmaf(yb[i], r01[1],
                      fmaf(yc[i], r23[0], fmaf(yd[i], r23[1], -C))));
            int swz = ((tok & 7) ^ (tok >> 3)) << 4;
            *(ushort_t*)(ytile + tok * 288 + ((c0 * 2) ^ swz)) =
                f2bf(fmaf(g4, v, be));
        }
    }
    __syncthreads();

    // ---- Phase 2: output GEMM (8 waves: wave = 16-o frag x 32 tok) ---------
    const int lo = lane & 15, hi = lane >> 4;
    const int ow = wv;                    // o-range [16*ow, 16*ow+16)
    const f32x4 zero = {0.f, 0.f, 0.f, 0.f};
    f32x4 acc[2] = {zero, zero};
    #pragma unroll
    for (int ks = 0; ks < 4; ++ks){
        short8 af = *(const short8*)(WO2 + (size_t)((ow * 4 + ks) * 64 + lane) * 8);
        #pragma unroll
        for (int t2 = 0; t2 < 2; ++t2){
            int tok = t2 * 16 + lo;
            int swz = ((tok & 7) ^ (tok >> 3)) << 4;
            short8 bfr = *(const short8*)(ytile + tok * 288 +
                            ((ks * 64 + hi * 16) ^ swz));
            acc[t2] = __builtin_amdgcn_mfma_f32_16x16x32_bf16(af, bfr, acc[t2], 0, 0, 0);
        }
    }
    {
        f32x4 bia = *(const f32x4*)(b_out + ow * 16 + hi * 4);
        #pragma unroll
        for (int t2 = 0; t2 < 2; ++t2){
            int l = m0 + t2 * 16 + lo;
            #pragma unroll
            for (int r = 0; r < 4; ++r){
                int o = ow * 16 + hi * 4 + r;
                out[((size_t)(b * 128 + o)) * LL + l] = acc[t2][r] + bia[r];
            }
        }
    }
}

// ---------------------------------------------------------------------------
extern "C" void kernel_launch(void* const* d_in, const int* in_sizes, int n_in,
                              void* d_out, int out_size, void* d_ws, size_t ws_size,
                              hipStream_t stream) {
    const float* x     = (const float*)d_in[0];
    const float* W_in  = (const float*)d_in[1];
    const float* b_in  = (const float*)d_in[2];
    const float* dw_w  = (const float*)d_in[3];
    const float* dw_b  = (const float*)d_in[4];
    const float* gamma = (const float*)d_in[5];
    const float* beta  = (const float*)d_in[6];
    const float* W_out = (const float*)d_in[7];
    const float* b_out = (const float*)d_in[8];
    float* out = (float*)d_out;

    // ws layout: UV (B,256,L) bf16 | 64B guard | W2 frag | WO2 frag | dwT
    ushort_t* UV  = (ushort_t*)d_ws;                       // 37,748,736 B
    ushort_t* W2  = UV + (size_t)BB * 256 * LL + 32;       // 256x128 bf16 frag
    ushort_t* WO2 = W2 + 256 * 128;                        // 128x128 bf16 frag
    float*    dwT = (float*)(WO2 + 128 * 128);             // [7][128] fp32

    k_prep<<<128, 256, 0, stream>>>(W_in, W_out, dw_w, W2, WO2, dwT);

    dim3 gA(LL / 64, BB);
    k_gemmA<<<gA, 256, 0, stream>>>(x, W2, b_in, UV);

    dim3 gM(288, BB);
    k_mixout<<<gM, 512, 0, stream>>>(UV, dwT, dw_b, gamma, beta,
                                     WO2, b_out, out);
}